// Round 13
// baseline (477.126 us; speedup 1.0000x reference)
//
#include <hip/hip_runtime.h>
#include <hip/hip_bf16.h>
#include <math.h>

// ---------------- problem constants ----------------
constexpr int B    = 8;
constexpr int NPG  = 10000;           // nodes per graph (stage 1)
constexpr int F    = 128;             // feature dim (F_IN == H == 128)
constexpr int OUTD = 64;
constexpr int E    = B * NPG * 16;    // 1,280,000 edges
constexpr int N0   = B * NPG;         // 80000
constexpr int K1   = 5000, K2 = 2500, K3 = 1250;
constexpr int N1   = B * K1;          // 40000
constexpr int N2   = B * K2;          // 20000
constexpr int N3   = B * K3;          // 10000
constexpr int PSPLIT = 256;           // summarize row-split (per graph)
constexpr int ESH  = E / 8;           // 160000 edges per graph (edge list graph-contiguous)
constexpr int KCH  = 32;              // chunks per graph for CSR build (8g x 32 = 256 blocks)
constexpr int CH   = ESH / KCH;       // 5000 edges per chunk

// ---------------- ws layout (float units) ----------------
constexpr size_t OFF_IN   = 0;                           // [80000][256] bf16 (mean|x)
constexpr size_t SZ_IN    = (size_t)N0 * 256 / 2;
constexpr size_t OFF_HB   = OFF_IN + SZ_IN;              // h bf16 [80000][128]
constexpr size_t SZ_HB    = (size_t)N0 * F / 2;          // 5.12M floats
// cnt/cur0 ([256][NPG] ints each, 5.12M total) ALIAS the hb region: they are
// fully consumed (k_csr_p / k_scan3c) before k_fuse writes hb.
constexpr size_t OFF_SC   = OFF_HB + SZ_HB;              // 80000 f32
constexpr size_t OFF_KEY  = OFF_SC + N0;                 // 80000 u32 (16B-aligned)
constexpr size_t OFF_MAP  = OFF_KEY + N0;                // 80000 i32 (nmap1 -> composed)
constexpr size_t OFF_MAP2 = OFF_MAP + N0;                // 40000 i32
constexpr size_t OFF_SEL1 = OFF_MAP2 + N1;               // 40000 i32 stage2->orig
constexpr size_t OFF_SEL2 = OFF_SEL1 + N1;               // 20000 i32 stage3->stage2
constexpr size_t OFF_SEL3 = OFF_SEL2 + N2;               // 10000 i32 final->stage3
constexpr size_t OFF_SOC  = OFF_SEL3 + N3;               // 20000 i32 stage3->orig
constexpr size_t OFF_VAL  = OFF_SOC + N2;                // 40000 f32
constexpr size_t OFF_CSR  = OFF_VAL + N1;                // E i32
constexpr size_t OFF_HSUM = OFF_CSR + E;                 // N0 i32
constexpr size_t OFF_INCL = OFF_HSUM + N0;               // N0 i32
constexpr size_t OFF_BSUM = OFF_INCL + N0;               // 512 i32
constexpr size_t OFF_RS   = OFF_BSUM + 512;              // N0+1 i32 (+pad)
constexpr size_t OFF_PART = OFF_RS + N0 + 64;            // B*PSPLIT*2*128 f32
constexpr size_t OFF_SUM  = OFF_PART + (size_t)B * PSPLIT * 2 * F;
constexpr size_t OFF_WCAT = OFF_SUM + (size_t)B * 2 * F; // 3 x [128][256] bf16
constexpr size_t OFF_MISC = OFF_WCAT + 3 * 128 * 256 / 2;

typedef __attribute__((ext_vector_type(8))) short short8;
typedef __attribute__((ext_vector_type(4))) float floatx4;

// ---------------- helpers ----------------
__device__ inline unsigned f2key(float f) {
    unsigned u = __float_as_uint(f);
    return (u & 0x80000000u) ? ~u : (u | 0x80000000u);
}
__device__ inline unsigned short f2b(float f) {      // RNE f32->bf16
    unsigned u = __float_as_uint(f);
    return (unsigned short)((u + 0x7FFFu + ((u >> 16) & 1u)) >> 16);
}
__device__ inline float b2f(unsigned short u) {
    return __uint_as_float((unsigned)u << 16);
}
// dword holding 2 bf16 -> 2 floats (1 VALU each)
__device__ inline float blo(unsigned u) { return __uint_as_float(u << 16); }
__device__ inline float bhi(unsigned u) { return __uint_as_float(u & 0xFFFF0000u); }

// ---------------- kernels ----------------
// all 3 stages' Wcat (bf16 concat) + pool-w norms in one launch
__global__ void k_prep3(const float* __restrict__ Wl1, const float* __restrict__ Wr1,
                        const float* __restrict__ Wl2, const float* __restrict__ Wr2,
                        const float* __restrict__ Wl3, const float* __restrict__ Wr3,
                        const float* __restrict__ p1, const float* __restrict__ p2,
                        const float* __restrict__ p3,
                        unsigned short* __restrict__ wcat, float* __restrict__ normv) {
    int b = blockIdx.x;
    if (b == 96) {
        int t = threadIdx.x;
        int which = t >> 6, lane = t & 63;
        if (which < 3) {
            const float* pw = (which == 0) ? p1 : (which == 1) ? p2 : p3;
            float v = 0.0f;
            for (int j = lane; j < F; j += 64) { float a = pw[j]; v += a * a; }
            for (int o = 32; o > 0; o >>= 1) v += __shfl_down(v, o);
            if (lane == 0) normv[which] = sqrtf(v);
        }
        return;
    }
    int stage = b >> 5;
    const float* Wl = (stage == 0) ? Wl1 : (stage == 1) ? Wl2 : Wl3;
    const float* Wr = (stage == 0) ? Wr1 : (stage == 1) ? Wr2 : Wr3;
    unsigned short* W = wcat + (size_t)stage * 128 * 256;
    int idx = ((b & 31) * 256 + threadIdx.x) * 4;
    int o = idx >> 8, k = idx & 255;
    const float* p = (k < 128) ? (Wl + o * 128 + k) : (Wr + o * 128 + (k - 128));
    float4 v = *(const float4*)p;
    ushort4 u;
    u.x = f2b(v.x); u.y = f2b(v.y); u.z = f2b(v.z); u.w = f2b(v.w);
    *(ushort4*)(W + idx) = u;
}

// x f32 -> bf16 into IN slab x-half
__global__ void k_cvt(const float* __restrict__ x, unsigned short* __restrict__ IN, int n) {
    long t = blockIdx.x * (long)blockDim.x + threadIdx.x;
    int i = (int)(t >> 5), lane = (int)(t & 31);
    if (i >= n) return;
    float4 v = ((const float4*)(x + (size_t)i * F))[lane];
    ushort4 u;
    u.x = f2b(v.x); u.y = f2b(v.y); u.z = f2b(v.z); u.w = f2b(v.w);
    *(ushort4*)(IN + (size_t)i * 256 + 128 + lane * 4) = u;
}

// -------- atomic-free CSR build (stage 1), 256 blocks (1/CU) --------
__global__ __launch_bounds__(1024) void k_hist_p(const int* __restrict__ dst,
                                                 int* __restrict__ cnt) {
    __shared__ int h[NPG];
    int b = blockIdx.x, g = b & 7, k = b >> 3;
    for (int i = threadIdx.x; i < NPG; i += 1024) h[i] = 0;
    __syncthreads();
    int base = g * ESH + k * CH;
    for (int i = threadIdx.x; i < CH; i += 1024) {
        int d = __builtin_nontemporal_load(dst + base + i) - g * NPG;
        atomicAdd(&h[d], 1);                        // LDS atomic
    }
    __syncthreads();
    int* o = cnt + (size_t)(g * KCH + k) * NPG;
    for (int i = threadIdx.x; i < NPG; i += 1024) o[i] = h[i];
}

// fused sumcnt + scan1: hsum[i] = sum over chunks; block-inclusive scan
__global__ __launch_bounds__(256) void k_scan1c(const int* __restrict__ cnt, int n,
                                                int* __restrict__ hsum,
                                                int* __restrict__ incl, int* __restrict__ bsum) {
    __shared__ int s[256];
    int i = blockIdx.x * 256 + threadIdx.x;
    int v = 0;
    if (i < n) {
        int g = i / NPG, l = i - g * NPG;
        const int* c = cnt + (size_t)g * KCH * NPG + l;
#pragma unroll
        for (int k = 0; k < KCH; k++) v += c[(size_t)k * NPG];
        hsum[i] = v;
    }
    s[threadIdx.x] = v;
    __syncthreads();
    for (int off = 1; off < 256; off <<= 1) {
        int t = s[threadIdx.x] + ((threadIdx.x >= off) ? s[threadIdx.x - off] : 0);
        __syncthreads();
        s[threadIdx.x] = t;
        __syncthreads();
    }
    if (i < n) incl[i] = s[threadIdx.x];
    if (threadIdx.x == 255) bsum[blockIdx.x] = s[255];
}

// rowstart + per-chunk cursor bases; block computes its own bsum prefix
__global__ __launch_bounds__(256) void k_scan3c(const int* __restrict__ in,
                                                const int* __restrict__ incl,
                                                const int* __restrict__ bsum,
                                                const int* __restrict__ cnt,
                                                int* __restrict__ rowstart,
                                                int* __restrict__ cur0) {
    __shared__ int red[256];
    int acc = 0;
    for (int t = threadIdx.x; t < blockIdx.x; t += 256) acc += bsum[t];
    red[threadIdx.x] = acc;
    __syncthreads();
    for (int off = 128; off > 0; off >>= 1) {
        if (threadIdx.x < off) red[threadIdx.x] += red[threadIdx.x + off];
        __syncthreads();
    }
    int pref = red[0];
    int i = blockIdx.x * 256 + threadIdx.x;
    if (i >= N0) return;
    int ex = incl[i] - in[i] + pref;
    rowstart[i] = ex;
    if (i == N0 - 1) rowstart[N0] = ex + in[i];
    int g = i / NPG, l = i - g * NPG;
    const int* c = cnt + (size_t)g * KCH * NPG + l;
    int* u = cur0 + (size_t)g * KCH * NPG + l;
    int run = ex;
#pragma unroll
    for (int k = 0; k < KCH; k++) {
        u[(size_t)k * NPG] = run;
        run += c[(size_t)k * NPG];
    }
}

// scatter src ids into csr using LDS cursors (no global atomics)
__global__ __launch_bounds__(1024) void k_csr_p(const int* __restrict__ src,
                                                const int* __restrict__ dst,
                                                const int* __restrict__ cur0,
                                                int* __restrict__ csr) {
    __shared__ int h[NPG];
    int b = blockIdx.x, g = b & 7, k = b >> 3;
    const int* u = cur0 + (size_t)(g * KCH + k) * NPG;
    for (int i = threadIdx.x; i < NPG; i += 1024) h[i] = u[i];
    __syncthreads();
    int base = g * ESH + k * CH;
    for (int i = threadIdx.x; i < CH; i += 1024) {
        int d = __builtin_nontemporal_load(dst + base + i) - g * NPG;
        int s = __builtin_nontemporal_load(src + base + i);
        int p = atomicAdd(&h[d], 1);                // LDS atomic
        csr[p] = s;
    }
}

// fused: compose orig->stage3 map; chain stage3->orig selection
__global__ void k_composechain(int* __restrict__ m1, const int* __restrict__ m2,
                               const int* __restrict__ s2, const int* __restrict__ s1,
                               int* __restrict__ soc, int n1, int n2) {
    int i = blockIdx.x * blockDim.x + threadIdx.x;
    if (i < n2) soc[i] = s1[s2[i]];
    if (i < n1) { int a = m1[i]; m1[i] = (a >= 0) ? m2[a] : -1; }
}

// FUSED aggregate + MFMA SAGE + scores. 128 rows/block, graph->XCD swizzle.
// Phase 1: 16-lane groups gather neighbor means -> swizzled LDS tile Am[128][128]
//          (granule ^= row&7: 2-way-max bank conflicts on write and read).
// Phase 2: 2-tile MFMA; A mean-half from LDS, x-half direct-global (L2-local).
// map==nullptr -> stage 1 (identity nodes, deg = row length).
__global__ __launch_bounds__(256) void k_fuse(
    const unsigned short* __restrict__ IN, const int* __restrict__ rowstart,
    const int* __restrict__ csr, const int* __restrict__ map,
    const int* __restrict__ orig_of,
    const unsigned short* __restrict__ Wcat, const float* __restrict__ bias,
    const float* __restrict__ poolw, const float* __restrict__ normv,
    unsigned short* __restrict__ hb, float* __restrict__ sc,
    unsigned* __restrict__ key, int npg, int relu) {
    __shared__ unsigned char smem[64 * 132 * 4];     // 33792B
    unsigned short* Am = (unsigned short*)smem;      // [128][128] bf16, swizzled
    float (*ep)[132] = (float(*)[132])smem;          // epilogue alias (after barrier)
    int tid = threadIdx.x;
    int g = blockIdx.x & 7, lb = blockIdx.x >> 3;
    int gbase = g * npg;

    // ---- phase 1: gather means into LDS ----
    {
        int sn = tid >> 4, lane = tid & 15;
        for (int it = 0; it < 8; it++) {
            int r = it * 16 + sn;                    // local row 0..127
            int lrow = lb * 128 + r;
            float a0 = 0, a1 = 0, a2 = 0, a3 = 0, a4 = 0, a5 = 0, a6 = 0, a7 = 0;
            float rd = 0.0f;
            if (lrow < npg) {
                int i = gbase + lrow;
                int d = 0;
                if (map) {
                    int o = orig_of[i];
                    int b = rowstart[o], e = rowstart[o + 1];
                    int j = b;
                    for (; j + 4 <= e; j += 4) {
                        int c0 = __builtin_nontemporal_load(csr + j);
                        int c1 = __builtin_nontemporal_load(csr + j + 1);
                        int c2 = __builtin_nontemporal_load(csr + j + 2);
                        int c3 = __builtin_nontemporal_load(csr + j + 3);
                        int m0 = map[c0], m1 = map[c1], m2 = map[c2], m3 = map[c3];
#pragma unroll
                        for (int t = 0; t < 4; t++) {
                            int s = (t == 0) ? m0 : (t == 1) ? m1 : (t == 2) ? m2 : m3;
                            if (s >= 0) {
                                uint4 u = *(const uint4*)(IN + (size_t)s * 256 + 128 + lane * 8);
                                a0 += blo(u.x); a1 += bhi(u.x);
                                a2 += blo(u.y); a3 += bhi(u.y);
                                a4 += blo(u.z); a5 += bhi(u.z);
                                a6 += blo(u.w); a7 += bhi(u.w);
                                d++;
                            }
                        }
                    }
                    for (; j < e; j++) {
                        int s = map[__builtin_nontemporal_load(csr + j)];
                        if (s >= 0) {
                            uint4 u = *(const uint4*)(IN + (size_t)s * 256 + 128 + lane * 8);
                            a0 += blo(u.x); a1 += bhi(u.x);
                            a2 += blo(u.y); a3 += bhi(u.y);
                            a4 += blo(u.z); a5 += bhi(u.z);
                            a6 += blo(u.w); a7 += bhi(u.w);
                            d++;
                        }
                    }
                } else {
                    int b = rowstart[i], e = rowstart[i + 1];
                    int j = b;
                    for (; j + 8 <= e; j += 8) {
                        int sx[8];
#pragma unroll
                        for (int t = 0; t < 8; t++) sx[t] = __builtin_nontemporal_load(csr + j + t);
                        uint4 ux[8];
#pragma unroll
                        for (int t = 0; t < 8; t++)
                            ux[t] = *(const uint4*)(IN + (size_t)sx[t] * 256 + 128 + lane * 8);
#pragma unroll
                        for (int t = 0; t < 8; t++) {
                            a0 += blo(ux[t].x); a1 += bhi(ux[t].x);
                            a2 += blo(ux[t].y); a3 += bhi(ux[t].y);
                            a4 += blo(ux[t].z); a5 += bhi(ux[t].z);
                            a6 += blo(ux[t].w); a7 += bhi(ux[t].w);
                        }
                    }
                    for (; j < e; j++) {
                        int s0 = __builtin_nontemporal_load(csr + j);
                        uint4 u = *(const uint4*)(IN + (size_t)s0 * 256 + 128 + lane * 8);
                        a0 += blo(u.x); a1 += bhi(u.x);
                        a2 += blo(u.y); a3 += bhi(u.y);
                        a4 += blo(u.z); a5 += bhi(u.z);
                        a6 += blo(u.w); a7 += bhi(u.w);
                    }
                    d = e - b;
                }
                rd = 1.0f / fmaxf((float)d, 1.0f);
            }
            short8 o8;
            o8[0] = (short)f2b(a0 * rd); o8[1] = (short)f2b(a1 * rd);
            o8[2] = (short)f2b(a2 * rd); o8[3] = (short)f2b(a3 * rd);
            o8[4] = (short)f2b(a4 * rd); o8[5] = (short)f2b(a5 * rd);
            o8[6] = (short)f2b(a6 * rd); o8[7] = (short)f2b(a7 * rd);
            int gr = lane ^ (r & 7);
            *(short8*)(Am + (size_t)r * 128 + gr * 8) = o8;
        }
    }
    __syncthreads();

    // ---- phase 2: MFMA (A: mean from LDS ks<4, x from global ks>=4) ----
    int wid = tid >> 6, lane = tid & 63;
    int q = lane >> 4, l15 = lane & 15;
    int rowloc0 = lb * 128 + wid * 32;

    floatx4 acc0[8], acc1[8];
#pragma unroll
    for (int c = 0; c < 8; c++) {
        acc0[c] = (floatx4){0.f, 0.f, 0.f, 0.f};
        acc1[c] = (floatx4){0.f, 0.f, 0.f, 0.f};
    }

    const unsigned short* bbase = Wcat + (size_t)l15 * 256 + q * 8;
    int r0 = wid * 32 + l15;            // LDS rows
    int r1 = r0 + 16;
    int lr0 = min(rowloc0 + l15, npg - 1);
    int lr1 = min(rowloc0 + 16 + l15, npg - 1);
    const unsigned short* x0p = IN + (size_t)(gbase + lr0) * 256 + 128 + q * 8;
    const unsigned short* x1p = IN + (size_t)(gbase + lr1) * 256 + 128 + q * 8;
#pragma unroll
    for (int ks = 0; ks < 8; ks++) {
        short8 a0, a1;
        if (ks < 4) {
            int g0 = (ks * 4 + q) ^ (r0 & 7);
            int g1 = (ks * 4 + q) ^ (r1 & 7);
            a0 = *(const short8*)(Am + (size_t)r0 * 128 + g0 * 8);
            a1 = *(const short8*)(Am + (size_t)r1 * 128 + g1 * 8);
        } else {
            a0 = *(const short8*)(x0p + ((ks - 4) << 5));
            a1 = *(const short8*)(x1p + ((ks - 4) << 5));
        }
#pragma unroll
        for (int c = 0; c < 8; c++) {
            short8 b = *(const short8*)(bbase + (c << 12) + (ks << 5));
            acc0[c] = __builtin_amdgcn_mfma_f32_16x16x32_bf16(a0, b, acc0[c], 0, 0, 0);
            acc1[c] = __builtin_amdgcn_mfma_f32_16x16x32_bf16(a1, b, acc1[c], 0, 0, 0);
        }
    }
    __syncthreads();   // Am reads complete before epilogue aliases smem

    float invn = 1.0f / (*normv);
#pragma unroll
    for (int t = 0; t < 2; t++) {
        float p0 = 0, p1 = 0, p2 = 0, p3 = 0;
#pragma unroll
        for (int c = 0; c < 8; c++) {
            int col = (c << 4) + l15;
            float bv = bias[col];
            float wv = poolw[col];
            floatx4 v = (t == 0) ? acc0[c] : acc1[c];
            v[0] += bv; v[1] += bv; v[2] += bv; v[3] += bv;
            if (relu) {
                v[0] = fmaxf(v[0], 0.f); v[1] = fmaxf(v[1], 0.f);
                v[2] = fmaxf(v[2], 0.f); v[3] = fmaxf(v[3], 0.f);
            }
            p0 += v[0] * wv; p1 += v[1] * wv; p2 += v[2] * wv; p3 += v[3] * wv;
            int lr = wid * 16 + q * 4;
            ep[lr + 0][col] = v[0];
            ep[lr + 1][col] = v[1];
            ep[lr + 2][col] = v[2];
            ep[lr + 3][col] = v[3];
        }
#pragma unroll
        for (int off = 1; off < 16; off <<= 1) {
            p0 += __shfl_xor(p0, off);
            p1 += __shfl_xor(p1, off);
            p2 += __shfl_xor(p2, off);
            p3 += __shfl_xor(p3, off);
        }
        if (l15 == 0) {
            float ps[4] = {p0, p1, p2, p3};
#pragma unroll
            for (int j = 0; j < 4; j++) {
                int lrow = rowloc0 + t * 16 + q * 4 + j;
                if (lrow < npg) {
                    float s = tanhf(ps[j] * invn);
                    sc[gbase + lrow] = s;
                    key[gbase + lrow] = f2key(s);
                }
            }
        }
        __syncthreads();
        // store 64 rows: ep row r -> local row lb*128 + (r>>4)*32 + t*16 + (r&15)
#pragma unroll
        for (int it = 0; it < 4; it++) {
            int task = it * 256 + tid;
            int r = task >> 4, grp = task & 15;
            int lrow = lb * 128 + (r >> 4) * 32 + t * 16 + (r & 15);
            if (lrow < npg) {
                float4 lo = *(const float4*)&ep[r][grp * 8];
                float4 hi = *(const float4*)&ep[r][grp * 8 + 4];
                short8 u;
                u[0] = (short)f2b(lo.x); u[1] = (short)f2b(lo.y);
                u[2] = (short)f2b(lo.z); u[3] = (short)f2b(lo.w);
                u[4] = (short)f2b(hi.x); u[5] = (short)f2b(hi.y);
                u[6] = (short)f2b(hi.z); u[7] = (short)f2b(hi.w);
                *(short8*)(hb + (size_t)(gbase + lrow) * 128 + grp * 8) = u;
            }
        }
        __syncthreads();
    }
}

// merged per-graph top-k: radix select then deterministic compaction
__global__ __launch_bounds__(1024) void k_topk(
    const unsigned* __restrict__ keys, const float* __restrict__ sc,
    int n_per, int k,
    int* __restrict__ node_map, int* __restrict__ sel_old, float* __restrict__ vals) {
    int g = blockIdx.x, tid = threadIdx.x;
    int lane = tid & 63, wid = tid >> 6;      // 16 waves
    const unsigned* kk = keys + (size_t)g * n_per;
    const float* ss = sc + (size_t)g * n_per;
    __shared__ int hist[256];
    __shared__ int suf[256];
    __shared__ unsigned sprefix;
    __shared__ int sr, sfound;
    __shared__ int we2[16], ws2[16];
    __shared__ int carry_pos, carry_eq;
    if (tid == 0) { sprefix = 0; sr = k; carry_pos = 0; carry_eq = 0; }
    __syncthreads();

    for (int b = 3; b >= 0; b--) {
        if (tid < 256) hist[tid] = 0;
        __syncthreads();
        unsigned pfx = sprefix;
        unsigned maskhi = (b == 3) ? 0u : (0xFFFFFFFFu << ((b + 1) * 8));
        for (int i = tid * 4; i < n_per; i += 4096) {
            uint4 kv4 = *(const uint4*)(kk + i);
#pragma unroll
            for (int j = 0; j < 4; j++) {
                unsigned kv = (j == 0) ? kv4.x : (j == 1) ? kv4.y : (j == 2) ? kv4.z : kv4.w;
                if ((kv & maskhi) == (pfx & maskhi))
                    atomicAdd(&hist[(kv >> (b * 8)) & 255], 1);
            }
        }
        __syncthreads();
        if (tid < 256) suf[tid] = hist[tid];
        __syncthreads();
        for (int off = 1; off < 256; off <<= 1) {
            int t = 0;
            if (tid < 256) t = suf[tid] + ((tid + off < 256) ? suf[tid + off] : 0);
            __syncthreads();
            if (tid < 256) suf[tid] = t;
            __syncthreads();
        }
        int r = sr;
        if (tid < 256) {
            int hi = (tid == 255) ? 0 : suf[tid + 1];
            if (hi < r && suf[tid] >= r) sfound = tid;   // unique
        }
        __syncthreads();
        if (tid == 0) {
            int v = sfound;
            int hi = (v == 255) ? 0 : suf[v + 1];
            sr = r - hi;
            sprefix = pfx | ((unsigned)v << (b * 8));
        }
        __syncthreads();
    }
    unsigned K = sprefix;
    int need = sr;
    __syncthreads();

    int nch = (n_per + 1023) >> 10;
    for (int ch = 0; ch < nch; ch++) {
        int i = (ch << 10) + tid;
        int valid = (i < n_per);
        unsigned kv = valid ? kk[i] : 0u;
        int is_gt = valid && (kv > K);
        int is_eq = valid && (kv == K);
        int e_incl = is_eq;
#pragma unroll
        for (int off = 1; off < 64; off <<= 1) {
            int t = __shfl_up(e_incl, off);
            e_incl += (lane >= off) ? t : 0;
        }
        if (lane == 63) we2[wid] = e_incl;
        __syncthreads();
        if (tid < 16) {
            int v = we2[tid];
#pragma unroll
            for (int off = 1; off < 16; off <<= 1) {
                int t = __shfl_up(v, off);
                v += ((int)tid >= off) ? t : 0;
            }
            we2[tid] = v;
        }
        __syncthreads();
        int eq_before = carry_eq + (e_incl - is_eq) + (wid ? we2[wid - 1] : 0);
        int sel = is_gt || (is_eq && eq_before < need);
        int s_incl = sel;
#pragma unroll
        for (int off = 1; off < 64; off <<= 1) {
            int t = __shfl_up(s_incl, off);
            s_incl += (lane >= off) ? t : 0;
        }
        if (lane == 63) ws2[wid] = s_incl;
        __syncthreads();
        if (tid < 16) {
            int v = ws2[tid];
#pragma unroll
            for (int off = 1; off < 16; off <<= 1) {
                int t = __shfl_up(v, off);
                v += ((int)tid >= off) ? t : 0;
            }
            ws2[tid] = v;
        }
        __syncthreads();
        int pos = carry_pos + (s_incl - sel) + (wid ? ws2[wid - 1] : 0);
        if (valid) {
            if (sel) {
                int ni = g * k + pos;
                node_map[(size_t)g * n_per + i] = ni;
                sel_old[ni] = g * n_per + i;
                vals[ni] = ss[i];
            } else {
                node_map[(size_t)g * n_per + i] = -1;
            }
        }
        __syncthreads();
        if (tid == 0) { carry_pos += ws2[15]; carry_eq += we2[15]; }
        __syncthreads();
    }
}

// gather selected h rows, scale by score, write bf16 into next IN x-half
__global__ void k_gatherb(const unsigned short* __restrict__ hb,
                          const int* __restrict__ sel_old,
                          const float* __restrict__ vals,
                          unsigned short* __restrict__ INnext, int m) {
    long t = blockIdx.x * (long)blockDim.x + threadIdx.x;
    int i = (int)(t >> 4), lane = (int)(t & 15);
    if (i >= m) return;
    int oi = sel_old[i];
    float v = vals[i];
    uint4 u = *(const uint4*)(hb + (size_t)oi * 128 + lane * 8);
    short8 o;
    o[0] = (short)f2b(blo(u.x) * v); o[1] = (short)f2b(bhi(u.x) * v);
    o[2] = (short)f2b(blo(u.y) * v); o[3] = (short)f2b(bhi(u.y) * v);
    o[4] = (short)f2b(blo(u.z) * v); o[5] = (short)f2b(bhi(u.z) * v);
    o[6] = (short)f2b(blo(u.w) * v); o[7] = (short)f2b(bhi(u.w) * v);
    *(short8*)(INnext + (size_t)i * 256 + 128 + lane * 8) = o;
}

// summarize partials: B*PSPLIT wave-blocks, lane = 2 features (ushort2)
__global__ __launch_bounds__(64) void k_partial2(const unsigned short* __restrict__ IN,
                                                 int k, float* __restrict__ part) {
    int g = blockIdx.x >> 8, s = blockIdx.x & (PSPLIT - 1);
    int lane = threadIdx.x;               // 64 lanes x ushort2 = 128 feats
    int rows = (k + PSPLIT - 1) / PSPLIT;
    int r0 = s * rows, r1 = min(k, r0 + rows);
    float s0 = 0, s1 = 0, m0 = -INFINITY, m1 = -INFINITY;
    for (int r = r0; r < r1; r++) {
        ushort2 u = *(const ushort2*)(IN + (size_t)(g * k + r) * 256 + 128 + lane * 2);
        float v0 = b2f(u.x), v1 = b2f(u.y);
        s0 += v0; s1 += v1;
        m0 = fmaxf(m0, v0); m1 = fmaxf(m1, v1);
    }
    size_t base = ((size_t)(g * PSPLIT + s) * 2) * F;
    *(float2*)&part[base + lane * 2] = make_float2(s0, s1);
    *(float2*)&part[base + F + lane * 2] = make_float2(m0, m1);
}

__global__ __launch_bounds__(256) void k_sumreduce2(const float* __restrict__ part, int k,
                                                    float* __restrict__ summary, int accum) {
    int g = blockIdx.x;
    int half = threadIdx.x >> 7, f = threadIdx.x & 127;  // 0=sum 1=max
    float sum = 0.0f, mx = -INFINITY;
    for (int s = 0; s < PSPLIT; s++) {
        float v = part[((size_t)(g * PSPLIT + s) * 2 + half) * F + f];
        sum += v;
        mx = fmaxf(mx, v);
    }
    float res = half ? mx : (sum / (float)k);
    int idx = g * 2 * F + half * F + f;
    if (accum) summary[idx] += res; else summary[idx] = res;
}

__global__ void k_out(const float* __restrict__ summary, const float* __restrict__ W,
                      const float* __restrict__ bias, float* __restrict__ out) {
    int g = blockIdx.x, j = threadIdx.x;  // 8 blocks x 64 threads
    float acc = bias[j];
    for (int t = 0; t < 2 * F; t++) acc += summary[g * 2 * F + t] * W[j * 2 * F + t];
    out[g * OUTD + j] = acc;
}

// ---------------- host launch ----------------
static inline int cdiv(long a, long b) { return (int)((a + b - 1) / b); }

extern "C" void kernel_launch(void* const* d_in, const int* in_sizes, int n_in,
                              void* d_out, int out_size, void* d_ws, size_t ws_size,
                              hipStream_t stream) {
    const float* x_in = (const float*)d_in[0];
    const int* ei     = (const int*)d_in[1];    // [2, E] -> src = ei, dst = ei+E
    const float* w1lW = (const float*)d_in[2];
    const float* w1lb = (const float*)d_in[3];
    const float* w1rW = (const float*)d_in[4];
    const float* p1w  = (const float*)d_in[5];
    const float* w2lW = (const float*)d_in[6];
    const float* w2lb = (const float*)d_in[7];
    const float* w2rW = (const float*)d_in[8];
    const float* p2w  = (const float*)d_in[9];
    const float* w3lW = (const float*)d_in[10];
    const float* w3lb = (const float*)d_in[11];
    const float* w3rW = (const float*)d_in[12];
    const float* p3w  = (const float*)d_in[13];
    const float* outW = (const float*)d_in[14];
    const float* outb = (const float*)d_in[15];
    float* out = (float*)d_out;

    float* ws = (float*)d_ws;
    unsigned short* INb  = (unsigned short*)(ws + OFF_IN);
    unsigned short* hb   = (unsigned short*)(ws + OFF_HB);
    // cnt/cur0 alias hb: consumed (csr build) before k_fuse writes hb
    int* cnt     = (int*)(ws + OFF_HB);
    int* cur0    = cnt + (size_t)B * KCH * NPG;   // 2.56M ints each; 5.12M = SZ_HB
    float* sc    = ws + OFF_SC;
    unsigned* key = (unsigned*)(ws + OFF_KEY);
    int* nmap1   = (int*)(ws + OFF_MAP);
    int* nmap2   = (int*)(ws + OFF_MAP2);
    int* selo1   = (int*)(ws + OFF_SEL1);
    int* selo2   = (int*)(ws + OFF_SEL2);
    int* selo3   = (int*)(ws + OFF_SEL3);
    int* soc     = (int*)(ws + OFF_SOC);
    float* vals  = ws + OFF_VAL;
    int* csr     = (int*)(ws + OFF_CSR);
    int* hsum    = (int*)(ws + OFF_HSUM);
    int* incl    = (int*)(ws + OFF_INCL);
    int* bsum    = (int*)(ws + OFF_BSUM);
    int* rs      = (int*)(ws + OFF_RS);
    float* part    = ws + OFF_PART;
    float* summary = ws + OFF_SUM;
    unsigned short* wcat = (unsigned short*)(ws + OFF_WCAT);
    int* misc_i  = (int*)(ws + OFF_MISC);
    float* normv = (float*)(misc_i + 20);

    const int* esrc = ei;
    const int* edst = ei + E;

    // ================= stage 1 =================
    {
        int n = N0, nb = cdiv(n, 256);
        k_prep3<<<97, 256, 0, stream>>>(w1lW, w1rW, w2lW, w2rW, w3lW, w3rW,
                                        p1w, p2w, p3w, wcat, normv);
        k_cvt<<<cdiv((long)n * 32, 256), 256, 0, stream>>>(x_in, INb, n);
        k_hist_p<<<B * KCH, 1024, 0, stream>>>(edst, cnt);
        k_scan1c<<<nb, 256, 0, stream>>>(cnt, n, hsum, incl, bsum);
        k_scan3c<<<nb, 256, 0, stream>>>(hsum, incl, bsum, cnt, rs, cur0);
        k_csr_p<<<B * KCH, 1024, 0, stream>>>(esrc, edst, cur0, csr);
        k_fuse<<<8 * cdiv(NPG, 128), 256, 0, stream>>>(INb, rs, csr, nullptr, nullptr,
                                                       wcat, w1lb, p1w, normv,
                                                       hb, sc, key, NPG, 0);
        k_topk<<<B, 1024, 0, stream>>>(key, sc, NPG, K1, nmap1, selo1, vals);
        k_gatherb<<<cdiv((long)N1 * 16, 256), 256, 0, stream>>>(hb, selo1, vals, INb, N1);
        k_partial2<<<B * PSPLIT, 64, 0, stream>>>(INb, K1, part);
        k_sumreduce2<<<B, 256, 0, stream>>>(part, K1, summary, 0);
    }

    // ================= stage 2 (stage-1 CSR + nmap1 predicate) =================
    {
        k_fuse<<<8 * cdiv(K1, 128), 256, 0, stream>>>(INb, rs, csr, nmap1, selo1,
                                                      wcat + 32768, w2lb, p2w, normv + 1,
                                                      hb, sc, key, K1, 1);
        k_topk<<<B, 1024, 0, stream>>>(key, sc, K1, K2, nmap2, selo2, vals);
        k_gatherb<<<cdiv((long)N2 * 16, 256), 256, 0, stream>>>(hb, selo2, vals, INb, N2);
        k_partial2<<<B * PSPLIT, 64, 0, stream>>>(INb, K2, part);
        k_sumreduce2<<<B, 256, 0, stream>>>(part, K2, summary, 1);
        k_composechain<<<cdiv(N0, 256), 256, 0, stream>>>(nmap1, nmap2, selo2, selo1, soc, N0, N2);
    }

    // ================= stage 3 (stage-1 CSR + composed map) =================
    {
        k_fuse<<<8 * cdiv(K2, 128), 256, 0, stream>>>(INb, rs, csr, nmap1, soc,
                                                      wcat + 65536, w3lb, p3w, normv + 2,
                                                      hb, sc, key, K2, 0);
        k_topk<<<B, 1024, 0, stream>>>(key, sc, K2, K3, nmap2, selo3, vals);
        k_gatherb<<<cdiv((long)N3 * 16, 256), 256, 0, stream>>>(hb, selo3, vals, INb, N3);
        k_partial2<<<B * PSPLIT, 64, 0, stream>>>(INb, K3, part);
        k_sumreduce2<<<B, 256, 0, stream>>>(part, K3, summary, 1);
    }

    // ================= output =================
    k_out<<<B, OUTD, 0, stream>>>(summary, outW, outb, out);
}

// Round 14
// 363.111 us; speedup vs baseline: 1.3140x; 1.3140x over previous
//
#include <hip/hip_runtime.h>
#include <hip/hip_bf16.h>
#include <math.h>

// ---------------- problem constants ----------------
constexpr int B    = 8;
constexpr int NPG  = 10000;           // nodes per graph (stage 1)
constexpr int F    = 128;             // feature dim (F_IN == H == 128)
constexpr int OUTD = 64;
constexpr int E    = B * NPG * 16;    // 1,280,000 edges
constexpr int N0   = B * NPG;         // 80000
constexpr int K1   = 5000, K2 = 2500, K3 = 1250;
constexpr int N1   = B * K1;          // 40000
constexpr int N2   = B * K2;          // 20000
constexpr int N3   = B * K3;          // 10000
constexpr int PSPLIT = 256;           // summarize row-split (per graph)
constexpr int ESH  = E / 8;           // 160000 edges per graph (edge list graph-contiguous)
constexpr int KCH  = 32;              // chunks per graph for CSR build (8g x 32 = 256 blocks)
constexpr int CH   = ESH / KCH;       // 5000 edges per chunk

// ---------------- ws layout (float units) ----------------
constexpr size_t OFF_IN   = 0;                           // [80000][256] bf16 (mean|x)
constexpr size_t SZ_IN    = (size_t)N0 * 256 / 2;
constexpr size_t OFF_HB   = OFF_IN + SZ_IN;              // h bf16 [80000][128]
constexpr size_t SZ_HB    = (size_t)N0 * F / 2;          // 5.12M floats
// cnt/cur0 ([256][NPG] ints each, 5.12M total) ALIAS the hb region: they are
// fully consumed (k_csr_p / k_scan3c) before k_sage_b writes hb.
constexpr size_t OFF_SC   = OFF_HB + SZ_HB;              // 80000 f32
constexpr size_t OFF_KEY  = OFF_SC + N0;                 // 80000 u32 (16B-aligned)
constexpr size_t OFF_MAP  = OFF_KEY + N0;                // 80000 i32 (nmap1 -> composed)
constexpr size_t OFF_MAP2 = OFF_MAP + N0;                // 40000 i32
constexpr size_t OFF_SEL1 = OFF_MAP2 + N1;               // 40000 i32 stage2->orig
constexpr size_t OFF_SEL2 = OFF_SEL1 + N1;               // 20000 i32 stage3->stage2
constexpr size_t OFF_SEL3 = OFF_SEL2 + N2;               // 10000 i32 final->stage3
constexpr size_t OFF_SOC  = OFF_SEL3 + N3;               // 20000 i32 stage3->orig
constexpr size_t OFF_VAL  = OFF_SOC + N2;                // 40000 f32
constexpr size_t OFF_CSR  = OFF_VAL + N1;                // E i32
constexpr size_t OFF_HSUM = OFF_CSR + E;                 // N0 i32
constexpr size_t OFF_INCL = OFF_HSUM + N0;               // N0 i32
constexpr size_t OFF_BSUM = OFF_INCL + N0;               // 512 i32
constexpr size_t OFF_RS   = OFF_BSUM + 512;              // N0+1 i32 (+pad)
constexpr size_t OFF_PART = OFF_RS + N0 + 64;            // B*PSPLIT*2*128 f32
constexpr size_t OFF_SUM  = OFF_PART + (size_t)B * PSPLIT * 2 * F;
constexpr size_t OFF_WCAT = OFF_SUM + (size_t)B * 2 * F; // 3 x [128][256] bf16
constexpr size_t OFF_MISC = OFF_WCAT + 3 * 128 * 256 / 2;

typedef __attribute__((ext_vector_type(8))) short short8;
typedef __attribute__((ext_vector_type(4))) float floatx4;

// ---------------- helpers ----------------
__device__ inline unsigned f2key(float f) {
    unsigned u = __float_as_uint(f);
    return (u & 0x80000000u) ? ~u : (u | 0x80000000u);
}
__device__ inline unsigned short f2b(float f) {      // RNE f32->bf16
    unsigned u = __float_as_uint(f);
    return (unsigned short)((u + 0x7FFFu + ((u >> 16) & 1u)) >> 16);
}
__device__ inline float b2f(unsigned short u) {
    return __uint_as_float((unsigned)u << 16);
}
// dword holding 2 bf16 -> 2 floats (1 VALU each)
__device__ inline float blo(unsigned u) { return __uint_as_float(u << 16); }
__device__ inline float bhi(unsigned u) { return __uint_as_float(u & 0xFFFF0000u); }

// ---------------- kernels ----------------
// all 3 stages' Wcat (bf16 concat) + pool-w norms in one launch
__global__ void k_prep3(const float* __restrict__ Wl1, const float* __restrict__ Wr1,
                        const float* __restrict__ Wl2, const float* __restrict__ Wr2,
                        const float* __restrict__ Wl3, const float* __restrict__ Wr3,
                        const float* __restrict__ p1, const float* __restrict__ p2,
                        const float* __restrict__ p3,
                        unsigned short* __restrict__ wcat, float* __restrict__ normv) {
    int b = blockIdx.x;
    if (b == 96) {
        int t = threadIdx.x;
        int which = t >> 6, lane = t & 63;
        if (which < 3) {
            const float* pw = (which == 0) ? p1 : (which == 1) ? p2 : p3;
            float v = 0.0f;
            for (int j = lane; j < F; j += 64) { float a = pw[j]; v += a * a; }
            for (int o = 32; o > 0; o >>= 1) v += __shfl_down(v, o);
            if (lane == 0) normv[which] = sqrtf(v);
        }
        return;
    }
    int stage = b >> 5;
    const float* Wl = (stage == 0) ? Wl1 : (stage == 1) ? Wl2 : Wl3;
    const float* Wr = (stage == 0) ? Wr1 : (stage == 1) ? Wr2 : Wr3;
    unsigned short* W = wcat + (size_t)stage * 128 * 256;
    int idx = ((b & 31) * 256 + threadIdx.x) * 4;
    int o = idx >> 8, k = idx & 255;
    const float* p = (k < 128) ? (Wl + o * 128 + k) : (Wr + o * 128 + (k - 128));
    float4 v = *(const float4*)p;
    ushort4 u;
    u.x = f2b(v.x); u.y = f2b(v.y); u.z = f2b(v.z); u.w = f2b(v.w);
    *(ushort4*)(W + idx) = u;
}

// x f32 -> bf16 into IN slab x-half
__global__ void k_cvt(const float* __restrict__ x, unsigned short* __restrict__ IN, int n) {
    long t = blockIdx.x * (long)blockDim.x + threadIdx.x;
    int i = (int)(t >> 5), lane = (int)(t & 31);
    if (i >= n) return;
    float4 v = ((const float4*)(x + (size_t)i * F))[lane];
    ushort4 u;
    u.x = f2b(v.x); u.y = f2b(v.y); u.z = f2b(v.z); u.w = f2b(v.w);
    *(ushort4*)(IN + (size_t)i * 256 + 128 + lane * 4) = u;
}

// -------- atomic-free CSR build (stage 1), 256 blocks (1/CU) --------
__global__ __launch_bounds__(1024) void k_hist_p(const int* __restrict__ dst,
                                                 int* __restrict__ cnt) {
    __shared__ int h[NPG];
    int b = blockIdx.x, g = b & 7, k = b >> 3;
    for (int i = threadIdx.x; i < NPG; i += 1024) h[i] = 0;
    __syncthreads();
    int base = g * ESH + k * CH;
    for (int i = threadIdx.x; i < CH; i += 1024) {
        int d = __builtin_nontemporal_load(dst + base + i) - g * NPG;
        atomicAdd(&h[d], 1);                        // LDS atomic
    }
    __syncthreads();
    int* o = cnt + (size_t)(g * KCH + k) * NPG;
    for (int i = threadIdx.x; i < NPG; i += 1024) o[i] = h[i];
}

// fused sumcnt + scan1: hsum[i] = sum over chunks; block-inclusive scan
__global__ __launch_bounds__(256) void k_scan1c(const int* __restrict__ cnt, int n,
                                                int* __restrict__ hsum,
                                                int* __restrict__ incl, int* __restrict__ bsum) {
    __shared__ int s[256];
    int i = blockIdx.x * 256 + threadIdx.x;
    int v = 0;
    if (i < n) {
        int g = i / NPG, l = i - g * NPG;
        const int* c = cnt + (size_t)g * KCH * NPG + l;
#pragma unroll
        for (int k = 0; k < KCH; k++) v += c[(size_t)k * NPG];
        hsum[i] = v;
    }
    s[threadIdx.x] = v;
    __syncthreads();
    for (int off = 1; off < 256; off <<= 1) {
        int t = s[threadIdx.x] + ((threadIdx.x >= off) ? s[threadIdx.x - off] : 0);
        __syncthreads();
        s[threadIdx.x] = t;
        __syncthreads();
    }
    if (i < n) incl[i] = s[threadIdx.x];
    if (threadIdx.x == 255) bsum[blockIdx.x] = s[255];
}

// rowstart + per-chunk cursor bases; block computes its own bsum prefix
__global__ __launch_bounds__(256) void k_scan3c(const int* __restrict__ in,
                                                const int* __restrict__ incl,
                                                const int* __restrict__ bsum,
                                                const int* __restrict__ cnt,
                                                int* __restrict__ rowstart,
                                                int* __restrict__ cur0) {
    __shared__ int red[256];
    int acc = 0;
    for (int t = threadIdx.x; t < blockIdx.x; t += 256) acc += bsum[t];
    red[threadIdx.x] = acc;
    __syncthreads();
    for (int off = 128; off > 0; off >>= 1) {
        if (threadIdx.x < off) red[threadIdx.x] += red[threadIdx.x + off];
        __syncthreads();
    }
    int pref = red[0];
    int i = blockIdx.x * 256 + threadIdx.x;
    if (i >= N0) return;
    int ex = incl[i] - in[i] + pref;
    rowstart[i] = ex;
    if (i == N0 - 1) rowstart[N0] = ex + in[i];
    int g = i / NPG, l = i - g * NPG;
    const int* c = cnt + (size_t)g * KCH * NPG + l;
    int* u = cur0 + (size_t)g * KCH * NPG + l;
    int run = ex;
#pragma unroll
    for (int k = 0; k < KCH; k++) {
        u[(size_t)k * NPG] = run;
        run += c[(size_t)k * NPG];
    }
}

// scatter src ids into csr using LDS cursors (no global atomics)
__global__ __launch_bounds__(1024) void k_csr_p(const int* __restrict__ src,
                                                const int* __restrict__ dst,
                                                const int* __restrict__ cur0,
                                                int* __restrict__ csr) {
    __shared__ int h[NPG];
    int b = blockIdx.x, g = b & 7, k = b >> 3;
    const int* u = cur0 + (size_t)(g * KCH + k) * NPG;
    for (int i = threadIdx.x; i < NPG; i += 1024) h[i] = u[i];
    __syncthreads();
    int base = g * ESH + k * CH;
    for (int i = threadIdx.x; i < CH; i += 1024) {
        int d = __builtin_nontemporal_load(dst + base + i) - g * NPG;
        int s = __builtin_nontemporal_load(src + base + i);
        int p = atomicAdd(&h[d], 1);                // LDS atomic
        csr[p] = s;
    }
}

// fused: compose orig->stage3 map; chain stage3->orig selection
__global__ void k_composechain(int* __restrict__ m1, const int* __restrict__ m2,
                               const int* __restrict__ s2, const int* __restrict__ s1,
                               int* __restrict__ soc, int n1, int n2) {
    int i = blockIdx.x * blockDim.x + threadIdx.x;
    if (i < n2) soc[i] = s1[s2[i]];
    if (i < n1) { int a = m1[i]; m1[i] = (a >= 0) ? m2[a] : -1; }
}

// stage-1 gather-aggregate bf16, graph->XCD swizzled.
// 16 lanes/node x uint4 (16B) loads, 8-deep MLP.
__global__ __launch_bounds__(256) void k_agg2b(unsigned short* __restrict__ IN,
                                               const int* __restrict__ rowstart,
                                               const int* __restrict__ csr, int npg) {
    int g = blockIdx.x & 7;
    int local = (blockIdx.x >> 3) * 16 + (threadIdx.x >> 4);
    int lane = threadIdx.x & 15;
    if (local >= npg) return;
    int i = g * npg + local;
    int b = rowstart[i], e = rowstart[i + 1];
    float a0 = 0, a1 = 0, a2 = 0, a3 = 0, a4 = 0, a5 = 0, a6 = 0, a7 = 0;
    int j = b;
    for (; j + 8 <= e; j += 8) {      // 8-way MLP
        int sx[8];
#pragma unroll
        for (int t = 0; t < 8; t++) sx[t] = __builtin_nontemporal_load(csr + j + t);
        uint4 ux[8];
#pragma unroll
        for (int t = 0; t < 8; t++)
            ux[t] = *(const uint4*)(IN + (size_t)sx[t] * 256 + 128 + lane * 8);
#pragma unroll
        for (int t = 0; t < 8; t++) {
            a0 += blo(ux[t].x); a1 += bhi(ux[t].x);
            a2 += blo(ux[t].y); a3 += bhi(ux[t].y);
            a4 += blo(ux[t].z); a5 += bhi(ux[t].z);
            a6 += blo(ux[t].w); a7 += bhi(ux[t].w);
        }
    }
    for (; j < e; j++) {
        int s0 = __builtin_nontemporal_load(csr + j);
        uint4 u = *(const uint4*)(IN + (size_t)s0 * 256 + 128 + lane * 8);
        a0 += blo(u.x); a1 += bhi(u.x);
        a2 += blo(u.y); a3 += bhi(u.y);
        a4 += blo(u.z); a5 += bhi(u.z);
        a6 += blo(u.w); a7 += bhi(u.w);
    }
    float rd = 1.0f / fmaxf((float)(e - b), 1.0f);
    short8 o;
    o[0] = (short)f2b(a0 * rd); o[1] = (short)f2b(a1 * rd);
    o[2] = (short)f2b(a2 * rd); o[3] = (short)f2b(a3 * rd);
    o[4] = (short)f2b(a4 * rd); o[5] = (short)f2b(a5 * rd);
    o[6] = (short)f2b(a6 * rd); o[7] = (short)f2b(a7 * rd);
    *(short8*)(IN + (size_t)i * 256 + lane * 8) = o;
}

// stages 2-3: pull over ORIGINAL neighbors of orig(i), predicated on map
__global__ __launch_bounds__(256) void k_agg2m(unsigned short* __restrict__ IN,
                                               const int* __restrict__ rowstart,
                                               const int* __restrict__ csr,
                                               const int* __restrict__ map,
                                               const int* __restrict__ orig_of, int npg) {
    int g = blockIdx.x & 7;
    int local = (blockIdx.x >> 3) * 16 + (threadIdx.x >> 4);
    int lane = threadIdx.x & 15;
    if (local >= npg) return;
    int i = g * npg + local;
    int o = orig_of[i];
    int b = rowstart[o], e = rowstart[o + 1];
    float a0 = 0, a1 = 0, a2 = 0, a3 = 0, a4 = 0, a5 = 0, a6 = 0, a7 = 0;
    int d = 0;
    int j = b;
    for (; j + 4 <= e; j += 4) {
        int c0 = __builtin_nontemporal_load(csr + j);
        int c1 = __builtin_nontemporal_load(csr + j + 1);
        int c2 = __builtin_nontemporal_load(csr + j + 2);
        int c3 = __builtin_nontemporal_load(csr + j + 3);
        int m0 = map[c0], m1 = map[c1], m2 = map[c2], m3 = map[c3];
#pragma unroll
        for (int t = 0; t < 4; t++) {
            int s = (t == 0) ? m0 : (t == 1) ? m1 : (t == 2) ? m2 : m3;
            if (s >= 0) {
                uint4 u = *(const uint4*)(IN + (size_t)s * 256 + 128 + lane * 8);
                a0 += blo(u.x); a1 += bhi(u.x);
                a2 += blo(u.y); a3 += bhi(u.y);
                a4 += blo(u.z); a5 += bhi(u.z);
                a6 += blo(u.w); a7 += bhi(u.w);
                d++;
            }
        }
    }
    for (; j < e; j++) {
        int c0 = __builtin_nontemporal_load(csr + j);
        int s0 = map[c0];
        if (s0 >= 0) {
            uint4 u = *(const uint4*)(IN + (size_t)s0 * 256 + 128 + lane * 8);
            a0 += blo(u.x); a1 += bhi(u.x);
            a2 += blo(u.y); a3 += bhi(u.y);
            a4 += blo(u.z); a5 += bhi(u.z);
            a6 += blo(u.w); a7 += bhi(u.w);
            d++;
        }
    }
    float rd = 1.0f / fmaxf((float)d, 1.0f);
    short8 out;
    out[0] = (short)f2b(a0 * rd); out[1] = (short)f2b(a1 * rd);
    out[2] = (short)f2b(a2 * rd); out[3] = (short)f2b(a3 * rd);
    out[4] = (short)f2b(a4 * rd); out[5] = (short)f2b(a5 * rd);
    out[6] = (short)f2b(a6 * rd); out[7] = (short)f2b(a7 * rd);
    *(short8*)(IN + (size_t)i * 256 + lane * 8) = out;
}

// MFMA SAGE + fused scores. Direct-global A fragments, 128 rows/block,
// 2 row-tiles per wave, graph->XCD swizzle (bid&7 == graph).
__global__ __launch_bounds__(256) void k_sage_b(
    const unsigned short* __restrict__ IN, const unsigned short* __restrict__ Wcat,
    const float* __restrict__ bias, const float* __restrict__ poolw,
    const float* __restrict__ normv,
    unsigned short* __restrict__ hb, float* __restrict__ sc,
    unsigned* __restrict__ key, int npg, int relu) {
    __shared__ float lds[64][132];
    int tid = threadIdx.x;
    int wid = tid >> 6, lane = tid & 63;
    int q = lane >> 4, l15 = lane & 15;
    int g = blockIdx.x & 7, lb = blockIdx.x >> 3;
    int gbase = g * npg;
    int rowloc0 = lb * 128 + wid * 32;          // wave's tile0 local row

    floatx4 acc0[8], acc1[8];
#pragma unroll
    for (int c = 0; c < 8; c++) {
        acc0[c] = (floatx4){0.f, 0.f, 0.f, 0.f};
        acc1[c] = (floatx4){0.f, 0.f, 0.f, 0.f};
    }

    const unsigned short* bbase = Wcat + (size_t)l15 * 256 + q * 8;
    int lr0 = min(rowloc0 + l15, npg - 1);
    int lr1 = min(rowloc0 + 16 + l15, npg - 1);
    const unsigned short* a0p = IN + (size_t)(gbase + lr0) * 256 + q * 8;
    const unsigned short* a1p = IN + (size_t)(gbase + lr1) * 256 + q * 8;
#pragma unroll
    for (int ks = 0; ks < 8; ks++) {
        short8 a0 = *(const short8*)(a0p + (ks << 5));
        short8 a1 = *(const short8*)(a1p + (ks << 5));
#pragma unroll
        for (int c = 0; c < 8; c++) {
            short8 b = *(const short8*)(bbase + (c << 12) + (ks << 5));
            acc0[c] = __builtin_amdgcn_mfma_f32_16x16x32_bf16(a0, b, acc0[c], 0, 0, 0);
            acc1[c] = __builtin_amdgcn_mfma_f32_16x16x32_bf16(a1, b, acc1[c], 0, 0, 0);
        }
    }

    float invn = 1.0f / (*normv);
#pragma unroll
    for (int t = 0; t < 2; t++) {
        float p0 = 0, p1 = 0, p2 = 0, p3 = 0;
#pragma unroll
        for (int c = 0; c < 8; c++) {
            int col = (c << 4) + l15;
            float bv = bias[col];
            float wv = poolw[col];
            floatx4 v = (t == 0) ? acc0[c] : acc1[c];
            v[0] += bv; v[1] += bv; v[2] += bv; v[3] += bv;
            if (relu) {
                v[0] = fmaxf(v[0], 0.f); v[1] = fmaxf(v[1], 0.f);
                v[2] = fmaxf(v[2], 0.f); v[3] = fmaxf(v[3], 0.f);
            }
            p0 += v[0] * wv; p1 += v[1] * wv; p2 += v[2] * wv; p3 += v[3] * wv;
            int lr = wid * 16 + q * 4;
            lds[lr + 0][col] = v[0];
            lds[lr + 1][col] = v[1];
            lds[lr + 2][col] = v[2];
            lds[lr + 3][col] = v[3];
        }
#pragma unroll
        for (int off = 1; off < 16; off <<= 1) {
            p0 += __shfl_xor(p0, off);
            p1 += __shfl_xor(p1, off);
            p2 += __shfl_xor(p2, off);
            p3 += __shfl_xor(p3, off);
        }
        if (l15 == 0) {
            float ps[4] = {p0, p1, p2, p3};
#pragma unroll
            for (int j = 0; j < 4; j++) {
                int lrow = rowloc0 + t * 16 + q * 4 + j;
                if (lrow < npg) {
                    float s = tanhf(ps[j] * invn);
                    sc[gbase + lrow] = s;
                    key[gbase + lrow] = f2key(s);
                }
            }
        }
        __syncthreads();
        // store 64 rows: lds row r -> local row lb*128 + (r>>4)*32 + t*16 + (r&15)
#pragma unroll
        for (int it = 0; it < 4; it++) {
            int task = it * 256 + tid;
            int r = task >> 4, grp = task & 15;
            int lrow = lb * 128 + (r >> 4) * 32 + t * 16 + (r & 15);
            if (lrow < npg) {
                float4 lo = *(const float4*)&lds[r][grp * 8];
                float4 hi = *(const float4*)&lds[r][grp * 8 + 4];
                short8 u;
                u[0] = (short)f2b(lo.x); u[1] = (short)f2b(lo.y);
                u[2] = (short)f2b(lo.z); u[3] = (short)f2b(lo.w);
                u[4] = (short)f2b(hi.x); u[5] = (short)f2b(hi.y);
                u[6] = (short)f2b(hi.z); u[7] = (short)f2b(hi.w);
                *(short8*)(hb + (size_t)(gbase + lrow) * 128 + grp * 8) = u;
            }
        }
        __syncthreads();
    }
}

// merged per-graph top-k: radix select then deterministic compaction
__global__ __launch_bounds__(1024) void k_topk(
    const unsigned* __restrict__ keys, const float* __restrict__ sc,
    int n_per, int k,
    int* __restrict__ node_map, int* __restrict__ sel_old, float* __restrict__ vals) {
    int g = blockIdx.x, tid = threadIdx.x;
    int lane = tid & 63, wid = tid >> 6;      // 16 waves
    const unsigned* kk = keys + (size_t)g * n_per;
    const float* ss = sc + (size_t)g * n_per;
    __shared__ int hist[256];
    __shared__ int suf[256];
    __shared__ unsigned sprefix;
    __shared__ int sr, sfound;
    __shared__ int we2[16], ws2[16];
    __shared__ int carry_pos, carry_eq;
    if (tid == 0) { sprefix = 0; sr = k; carry_pos = 0; carry_eq = 0; }
    __syncthreads();

    for (int b = 3; b >= 0; b--) {
        if (tid < 256) hist[tid] = 0;
        __syncthreads();
        unsigned pfx = sprefix;
        unsigned maskhi = (b == 3) ? 0u : (0xFFFFFFFFu << ((b + 1) * 8));
        for (int i = tid * 4; i < n_per; i += 4096) {
            uint4 kv4 = *(const uint4*)(kk + i);
#pragma unroll
            for (int j = 0; j < 4; j++) {
                unsigned kv = (j == 0) ? kv4.x : (j == 1) ? kv4.y : (j == 2) ? kv4.z : kv4.w;
                if ((kv & maskhi) == (pfx & maskhi))
                    atomicAdd(&hist[(kv >> (b * 8)) & 255], 1);
            }
        }
        __syncthreads();
        if (tid < 256) suf[tid] = hist[tid];
        __syncthreads();
        for (int off = 1; off < 256; off <<= 1) {
            int t = 0;
            if (tid < 256) t = suf[tid] + ((tid + off < 256) ? suf[tid + off] : 0);
            __syncthreads();
            if (tid < 256) suf[tid] = t;
            __syncthreads();
        }
        int r = sr;
        if (tid < 256) {
            int hi = (tid == 255) ? 0 : suf[tid + 1];
            if (hi < r && suf[tid] >= r) sfound = tid;   // unique
        }
        __syncthreads();
        if (tid == 0) {
            int v = sfound;
            int hi = (v == 255) ? 0 : suf[v + 1];
            sr = r - hi;
            sprefix = pfx | ((unsigned)v << (b * 8));
        }
        __syncthreads();
    }
    unsigned K = sprefix;
    int need = sr;
    __syncthreads();

    int nch = (n_per + 1023) >> 10;
    for (int ch = 0; ch < nch; ch++) {
        int i = (ch << 10) + tid;
        int valid = (i < n_per);
        unsigned kv = valid ? kk[i] : 0u;
        int is_gt = valid && (kv > K);
        int is_eq = valid && (kv == K);
        int e_incl = is_eq;
#pragma unroll
        for (int off = 1; off < 64; off <<= 1) {
            int t = __shfl_up(e_incl, off);
            e_incl += (lane >= off) ? t : 0;
        }
        if (lane == 63) we2[wid] = e_incl;
        __syncthreads();
        if (tid < 16) {
            int v = we2[tid];
#pragma unroll
            for (int off = 1; off < 16; off <<= 1) {
                int t = __shfl_up(v, off);
                v += ((int)tid >= off) ? t : 0;
            }
            we2[tid] = v;
        }
        __syncthreads();
        int eq_before = carry_eq + (e_incl - is_eq) + (wid ? we2[wid - 1] : 0);
        int sel = is_gt || (is_eq && eq_before < need);
        int s_incl = sel;
#pragma unroll
        for (int off = 1; off < 64; off <<= 1) {
            int t = __shfl_up(s_incl, off);
            s_incl += (lane >= off) ? t : 0;
        }
        if (lane == 63) ws2[wid] = s_incl;
        __syncthreads();
        if (tid < 16) {
            int v = ws2[tid];
#pragma unroll
            for (int off = 1; off < 16; off <<= 1) {
                int t = __shfl_up(v, off);
                v += ((int)tid >= off) ? t : 0;
            }
            ws2[tid] = v;
        }
        __syncthreads();
        int pos = carry_pos + (s_incl - sel) + (wid ? ws2[wid - 1] : 0);
        if (valid) {
            if (sel) {
                int ni = g * k + pos;
                node_map[(size_t)g * n_per + i] = ni;
                sel_old[ni] = g * n_per + i;
                vals[ni] = ss[i];
            } else {
                node_map[(size_t)g * n_per + i] = -1;
            }
        }
        __syncthreads();
        if (tid == 0) { carry_pos += ws2[15]; carry_eq += we2[15]; }
        __syncthreads();
    }
}

// gather selected h rows, scale by score, write bf16 into next IN x-half
__global__ void k_gatherb(const unsigned short* __restrict__ hb,
                          const int* __restrict__ sel_old,
                          const float* __restrict__ vals,
                          unsigned short* __restrict__ INnext, int m) {
    long t = blockIdx.x * (long)blockDim.x + threadIdx.x;
    int i = (int)(t >> 4), lane = (int)(t & 15);
    if (i >= m) return;
    int oi = sel_old[i];
    float v = vals[i];
    uint4 u = *(const uint4*)(hb + (size_t)oi * 128 + lane * 8);
    short8 o;
    o[0] = (short)f2b(blo(u.x) * v); o[1] = (short)f2b(bhi(u.x) * v);
    o[2] = (short)f2b(blo(u.y) * v); o[3] = (short)f2b(bhi(u.y) * v);
    o[4] = (short)f2b(blo(u.z) * v); o[5] = (short)f2b(bhi(u.z) * v);
    o[6] = (short)f2b(blo(u.w) * v); o[7] = (short)f2b(bhi(u.w) * v);
    *(short8*)(INnext + (size_t)i * 256 + 128 + lane * 8) = o;
}

// summarize partials: B*PSPLIT wave-blocks, lane = 2 features (ushort2)
__global__ __launch_bounds__(64) void k_partial2(const unsigned short* __restrict__ IN,
                                                 int k, float* __restrict__ part) {
    int g = blockIdx.x >> 8, s = blockIdx.x & (PSPLIT - 1);
    int lane = threadIdx.x;               // 64 lanes x ushort2 = 128 feats
    int rows = (k + PSPLIT - 1) / PSPLIT;
    int r0 = s * rows, r1 = min(k, r0 + rows);
    float s0 = 0, s1 = 0, m0 = -INFINITY, m1 = -INFINITY;
    for (int r = r0; r < r1; r++) {
        ushort2 u = *(const ushort2*)(IN + (size_t)(g * k + r) * 256 + 128 + lane * 2);
        float v0 = b2f(u.x), v1 = b2f(u.y);
        s0 += v0; s1 += v1;
        m0 = fmaxf(m0, v0); m1 = fmaxf(m1, v1);
    }
    size_t base = ((size_t)(g * PSPLIT + s) * 2) * F;
    *(float2*)&part[base + lane * 2] = make_float2(s0, s1);
    *(float2*)&part[base + F + lane * 2] = make_float2(m0, m1);
}

__global__ __launch_bounds__(256) void k_sumreduce2(const float* __restrict__ part, int k,
                                                    float* __restrict__ summary, int accum) {
    int g = blockIdx.x;
    int half = threadIdx.x >> 7, f = threadIdx.x & 127;  // 0=sum 1=max
    float sum = 0.0f, mx = -INFINITY;
    for (int s = 0; s < PSPLIT; s++) {
        float v = part[((size_t)(g * PSPLIT + s) * 2 + half) * F + f];
        sum += v;
        mx = fmaxf(mx, v);
    }
    float res = half ? mx : (sum / (float)k);
    int idx = g * 2 * F + half * F + f;
    if (accum) summary[idx] += res; else summary[idx] = res;
}

__global__ void k_out(const float* __restrict__ summary, const float* __restrict__ W,
                      const float* __restrict__ bias, float* __restrict__ out) {
    int g = blockIdx.x, j = threadIdx.x;  // 8 blocks x 64 threads
    float acc = bias[j];
    for (int t = 0; t < 2 * F; t++) acc += summary[g * 2 * F + t] * W[j * 2 * F + t];
    out[g * OUTD + j] = acc;
}

// ---------------- host launch ----------------
static inline int cdiv(long a, long b) { return (int)((a + b - 1) / b); }

extern "C" void kernel_launch(void* const* d_in, const int* in_sizes, int n_in,
                              void* d_out, int out_size, void* d_ws, size_t ws_size,
                              hipStream_t stream) {
    const float* x_in = (const float*)d_in[0];
    const int* ei     = (const int*)d_in[1];    // [2, E] -> src = ei, dst = ei+E
    const float* w1lW = (const float*)d_in[2];
    const float* w1lb = (const float*)d_in[3];
    const float* w1rW = (const float*)d_in[4];
    const float* p1w  = (const float*)d_in[5];
    const float* w2lW = (const float*)d_in[6];
    const float* w2lb = (const float*)d_in[7];
    const float* w2rW = (const float*)d_in[8];
    const float* p2w  = (const float*)d_in[9];
    const float* w3lW = (const float*)d_in[10];
    const float* w3lb = (const float*)d_in[11];
    const float* w3rW = (const float*)d_in[12];
    const float* p3w  = (const float*)d_in[13];
    const float* outW = (const float*)d_in[14];
    const float* outb = (const float*)d_in[15];
    float* out = (float*)d_out;

    float* ws = (float*)d_ws;
    unsigned short* INb  = (unsigned short*)(ws + OFF_IN);
    unsigned short* hb   = (unsigned short*)(ws + OFF_HB);
    // cnt/cur0 alias hb: consumed (csr build) before sage writes hb
    int* cnt     = (int*)(ws + OFF_HB);
    int* cur0    = cnt + (size_t)B * KCH * NPG;   // 2.56M ints each; 5.12M = SZ_HB
    float* sc    = ws + OFF_SC;
    unsigned* key = (unsigned*)(ws + OFF_KEY);
    int* nmap1   = (int*)(ws + OFF_MAP);
    int* nmap2   = (int*)(ws + OFF_MAP2);
    int* selo1   = (int*)(ws + OFF_SEL1);
    int* selo2   = (int*)(ws + OFF_SEL2);
    int* selo3   = (int*)(ws + OFF_SEL3);
    int* soc     = (int*)(ws + OFF_SOC);
    float* vals  = ws + OFF_VAL;
    int* csr     = (int*)(ws + OFF_CSR);
    int* hsum    = (int*)(ws + OFF_HSUM);
    int* incl    = (int*)(ws + OFF_INCL);
    int* bsum    = (int*)(ws + OFF_BSUM);
    int* rs      = (int*)(ws + OFF_RS);
    float* part    = ws + OFF_PART;
    float* summary = ws + OFF_SUM;
    unsigned short* wcat = (unsigned short*)(ws + OFF_WCAT);
    int* misc_i  = (int*)(ws + OFF_MISC);
    float* normv = (float*)(misc_i + 20);

    const int* esrc = ei;
    const int* edst = ei + E;

    // ================= stage 1 =================
    {
        int n = N0, nb = cdiv(n, 256);
        k_prep3<<<97, 256, 0, stream>>>(w1lW, w1rW, w2lW, w2rW, w3lW, w3rW,
                                        p1w, p2w, p3w, wcat, normv);
        k_cvt<<<cdiv((long)n * 32, 256), 256, 0, stream>>>(x_in, INb, n);
        k_hist_p<<<B * KCH, 1024, 0, stream>>>(edst, cnt);
        k_scan1c<<<nb, 256, 0, stream>>>(cnt, n, hsum, incl, bsum);
        k_scan3c<<<nb, 256, 0, stream>>>(hsum, incl, bsum, cnt, rs, cur0);
        k_csr_p<<<B * KCH, 1024, 0, stream>>>(esrc, edst, cur0, csr);
        k_agg2b<<<8 * cdiv(NPG, 16), 256, 0, stream>>>(INb, rs, csr, NPG);
        k_sage_b<<<8 * cdiv(NPG, 128), 256, 0, stream>>>(INb, wcat, w1lb, p1w, normv,
                                                         hb, sc, key, NPG, 0);
        k_topk<<<B, 1024, 0, stream>>>(key, sc, NPG, K1, nmap1, selo1, vals);
        k_gatherb<<<cdiv((long)N1 * 16, 256), 256, 0, stream>>>(hb, selo1, vals, INb, N1);
        k_partial2<<<B * PSPLIT, 64, 0, stream>>>(INb, K1, part);
        k_sumreduce2<<<B, 256, 0, stream>>>(part, K1, summary, 0);
    }

    // ================= stage 2 (stage-1 CSR + nmap1 predicate) =================
    {
        k_agg2m<<<8 * cdiv(K1, 16), 256, 0, stream>>>(INb, rs, csr, nmap1, selo1, K1);
        k_sage_b<<<8 * cdiv(K1, 128), 256, 0, stream>>>(INb, wcat + 32768, w2lb, p2w, normv + 1,
                                                        hb, sc, key, K1, 1);
        k_topk<<<B, 1024, 0, stream>>>(key, sc, K1, K2, nmap2, selo2, vals);
        k_gatherb<<<cdiv((long)N2 * 16, 256), 256, 0, stream>>>(hb, selo2, vals, INb, N2);
        k_partial2<<<B * PSPLIT, 64, 0, stream>>>(INb, K2, part);
        k_sumreduce2<<<B, 256, 0, stream>>>(part, K2, summary, 1);
        k_composechain<<<cdiv(N0, 256), 256, 0, stream>>>(nmap1, nmap2, selo2, selo1, soc, N0, N2);
    }

    // ================= stage 3 (stage-1 CSR + composed map) =================
    {
        k_agg2m<<<8 * cdiv(K2, 16), 256, 0, stream>>>(INb, rs, csr, nmap1, soc, K2);
        k_sage_b<<<8 * cdiv(K2, 128), 256, 0, stream>>>(INb, wcat + 65536, w3lb, p3w, normv + 2,
                                                        hb, sc, key, K2, 0);
        k_topk<<<B, 1024, 0, stream>>>(key, sc, K2, K3, nmap2, selo3, vals);
        k_gatherb<<<cdiv((long)N3 * 16, 256), 256, 0, stream>>>(hb, selo3, vals, INb, N3);
        k_partial2<<<B * PSPLIT, 64, 0, stream>>>(INb, K3, part);
        k_sumreduce2<<<B, 256, 0, stream>>>(part, K3, summary, 1);
    }

    // ================= output =================
    k_out<<<B, OUTD, 0, stream>>>(summary, outW, outb, out);
}

// Round 15
// 361.414 us; speedup vs baseline: 1.3202x; 1.0047x over previous
//
#include <hip/hip_runtime.h>
#include <hip/hip_bf16.h>
#include <math.h>

// ---------------- problem constants ----------------
constexpr int B    = 8;
constexpr int NPG  = 10000;           // nodes per graph (stage 1)
constexpr int F    = 128;             // feature dim (F_IN == H == 128)
constexpr int OUTD = 64;
constexpr int E    = B * NPG * 16;    // 1,280,000 edges
constexpr int N0   = B * NPG;         // 80000
constexpr int K1   = 5000, K2 = 2500, K3 = 1250;
constexpr int N1   = B * K1;          // 40000
constexpr int N2   = B * K2;          // 20000
constexpr int N3   = B * K3;          // 10000
constexpr int PSPLIT = 256;           // summarize row-split (per graph)
constexpr int ESH  = E / 8;           // 160000 edges per graph (edge list graph-contiguous)
constexpr int KCH  = 32;              // chunks per graph for CSR build (8g x 32 = 256 blocks)
constexpr int CH   = ESH / KCH;       // 5000 edges per chunk

// ---------------- ws layout (float units) ----------------
constexpr size_t OFF_IN   = 0;                           // [80000][256] bf16 (mean|x)
constexpr size_t SZ_IN    = (size_t)N0 * 256 / 2;
constexpr size_t OFF_HB   = OFF_IN + SZ_IN;              // h bf16 [80000][128]
constexpr size_t SZ_HB    = (size_t)N0 * F / 2;          // 5.12M floats
// cnt/cur0 ([256][NPG] ints each, 5.12M total) ALIAS the hb region: they are
// fully consumed (k_csr_p / k_scan3c) before k_sage_b writes hb.
constexpr size_t OFF_SC   = OFF_HB + SZ_HB;              // 80000 f32
constexpr size_t OFF_KEY  = OFF_SC + N0;                 // 80000 u32 (16B-aligned)
constexpr size_t OFF_MAP  = OFF_KEY + N0;                // 80000 i32 (nmap1 -> composed)
constexpr size_t OFF_MAP2 = OFF_MAP + N0;                // 40000 i32
constexpr size_t OFF_SEL1 = OFF_MAP2 + N1;               // 40000 i32 stage2->orig
constexpr size_t OFF_SEL2 = OFF_SEL1 + N1;               // 20000 i32 stage3->stage2
constexpr size_t OFF_SEL3 = OFF_SEL2 + N2;               // 10000 i32 final->stage3
constexpr size_t OFF_SOC  = OFF_SEL3 + N3;               // 20000 i32 stage3->orig
constexpr size_t OFF_VAL  = OFF_SOC + N2;                // 40000 f32
constexpr size_t OFF_CSR  = OFF_VAL + N1;                // E i32
constexpr size_t OFF_HSUM = OFF_CSR + E;                 // N0 i32
constexpr size_t OFF_INCL = OFF_HSUM + N0;               // N0 i32
constexpr size_t OFF_BSUM = OFF_INCL + N0;               // 512 i32
constexpr size_t OFF_RS   = OFF_BSUM + 512;              // N0+1 i32 (+pad)
constexpr size_t OFF_PART = OFF_RS + N0 + 64;            // B*PSPLIT*2*128 f32
constexpr size_t OFF_SUM  = OFF_PART + (size_t)B * PSPLIT * 2 * F;
constexpr size_t OFF_WCAT = OFF_SUM + (size_t)B * 2 * F; // 3 x [128][256] bf16
constexpr size_t OFF_MISC = OFF_WCAT + 3 * 128 * 256 / 2;

typedef __attribute__((ext_vector_type(8))) short short8;
typedef __attribute__((ext_vector_type(4))) float floatx4;

// ---------------- helpers ----------------
__device__ inline unsigned f2key(float f) {
    unsigned u = __float_as_uint(f);
    return (u & 0x80000000u) ? ~u : (u | 0x80000000u);
}
__device__ inline unsigned short f2b(float f) {      // RNE f32->bf16
    unsigned u = __float_as_uint(f);
    return (unsigned short)((u + 0x7FFFu + ((u >> 16) & 1u)) >> 16);
}
__device__ inline float b2f(unsigned short u) {
    return __uint_as_float((unsigned)u << 16);
}
// dword holding 2 bf16 -> 2 floats (1 VALU each)
__device__ inline float blo(unsigned u) { return __uint_as_float(u << 16); }
__device__ inline float bhi(unsigned u) { return __uint_as_float(u & 0xFFFF0000u); }

// ---------------- kernels ----------------
// all 3 stages' Wcat (bf16 concat) + pool-w norms in one launch
__global__ void k_prep3(const float* __restrict__ Wl1, const float* __restrict__ Wr1,
                        const float* __restrict__ Wl2, const float* __restrict__ Wr2,
                        const float* __restrict__ Wl3, const float* __restrict__ Wr3,
                        const float* __restrict__ p1, const float* __restrict__ p2,
                        const float* __restrict__ p3,
                        unsigned short* __restrict__ wcat, float* __restrict__ normv) {
    int b = blockIdx.x;
    if (b == 96) {
        int t = threadIdx.x;
        int which = t >> 6, lane = t & 63;
        if (which < 3) {
            const float* pw = (which == 0) ? p1 : (which == 1) ? p2 : p3;
            float v = 0.0f;
            for (int j = lane; j < F; j += 64) { float a = pw[j]; v += a * a; }
            for (int o = 32; o > 0; o >>= 1) v += __shfl_down(v, o);
            if (lane == 0) normv[which] = sqrtf(v);
        }
        return;
    }
    int stage = b >> 5;
    const float* Wl = (stage == 0) ? Wl1 : (stage == 1) ? Wl2 : Wl3;
    const float* Wr = (stage == 0) ? Wr1 : (stage == 1) ? Wr2 : Wr3;
    unsigned short* W = wcat + (size_t)stage * 128 * 256;
    int idx = ((b & 31) * 256 + threadIdx.x) * 4;
    int o = idx >> 8, k = idx & 255;
    const float* p = (k < 128) ? (Wl + o * 128 + k) : (Wr + o * 128 + (k - 128));
    float4 v = *(const float4*)p;
    ushort4 u;
    u.x = f2b(v.x); u.y = f2b(v.y); u.z = f2b(v.z); u.w = f2b(v.w);
    *(ushort4*)(W + idx) = u;
}

// x f32 -> bf16 into IN slab x-half
__global__ void k_cvt(const float* __restrict__ x, unsigned short* __restrict__ IN, int n) {
    long t = blockIdx.x * (long)blockDim.x + threadIdx.x;
    int i = (int)(t >> 5), lane = (int)(t & 31);
    if (i >= n) return;
    float4 v = ((const float4*)(x + (size_t)i * F))[lane];
    ushort4 u;
    u.x = f2b(v.x); u.y = f2b(v.y); u.z = f2b(v.z); u.w = f2b(v.w);
    *(ushort4*)(IN + (size_t)i * 256 + 128 + lane * 4) = u;
}

// -------- atomic-free CSR build (stage 1), 256 blocks (1/CU) --------
__global__ __launch_bounds__(1024) void k_hist_p(const int* __restrict__ dst,
                                                 int* __restrict__ cnt) {
    __shared__ int h[NPG];
    int b = blockIdx.x, g = b & 7, k = b >> 3;
    for (int i = threadIdx.x; i < NPG; i += 1024) h[i] = 0;
    __syncthreads();
    int base = g * ESH + k * CH;
    for (int i = threadIdx.x; i < CH; i += 1024) {
        int d = __builtin_nontemporal_load(dst + base + i) - g * NPG;
        atomicAdd(&h[d], 1);                        // LDS atomic
    }
    __syncthreads();
    int* o = cnt + (size_t)(g * KCH + k) * NPG;
    for (int i = threadIdx.x; i < NPG; i += 1024) o[i] = h[i];
}

// fused sumcnt + scan1: hsum[i] = sum over chunks; block-inclusive scan
__global__ __launch_bounds__(256) void k_scan1c(const int* __restrict__ cnt, int n,
                                                int* __restrict__ hsum,
                                                int* __restrict__ incl, int* __restrict__ bsum) {
    __shared__ int s[256];
    int i = blockIdx.x * 256 + threadIdx.x;
    int v = 0;
    if (i < n) {
        int g = i / NPG, l = i - g * NPG;
        const int* c = cnt + (size_t)g * KCH * NPG + l;
#pragma unroll
        for (int k = 0; k < KCH; k++) v += c[(size_t)k * NPG];
        hsum[i] = v;
    }
    s[threadIdx.x] = v;
    __syncthreads();
    for (int off = 1; off < 256; off <<= 1) {
        int t = s[threadIdx.x] + ((threadIdx.x >= off) ? s[threadIdx.x - off] : 0);
        __syncthreads();
        s[threadIdx.x] = t;
        __syncthreads();
    }
    if (i < n) incl[i] = s[threadIdx.x];
    if (threadIdx.x == 255) bsum[blockIdx.x] = s[255];
}

// rowstart + per-chunk cursor bases; block computes its own bsum prefix
__global__ __launch_bounds__(256) void k_scan3c(const int* __restrict__ in,
                                                const int* __restrict__ incl,
                                                const int* __restrict__ bsum,
                                                const int* __restrict__ cnt,
                                                int* __restrict__ rowstart,
                                                int* __restrict__ cur0) {
    __shared__ int red[256];
    int acc = 0;
    for (int t = threadIdx.x; t < blockIdx.x; t += 256) acc += bsum[t];
    red[threadIdx.x] = acc;
    __syncthreads();
    for (int off = 128; off > 0; off >>= 1) {
        if (threadIdx.x < off) red[threadIdx.x] += red[threadIdx.x + off];
        __syncthreads();
    }
    int pref = red[0];
    int i = blockIdx.x * 256 + threadIdx.x;
    if (i >= N0) return;
    int ex = incl[i] - in[i] + pref;
    rowstart[i] = ex;
    if (i == N0 - 1) rowstart[N0] = ex + in[i];
    int g = i / NPG, l = i - g * NPG;
    const int* c = cnt + (size_t)g * KCH * NPG + l;
    int* u = cur0 + (size_t)g * KCH * NPG + l;
    int run = ex;
#pragma unroll
    for (int k = 0; k < KCH; k++) {
        u[(size_t)k * NPG] = run;
        run += c[(size_t)k * NPG];
    }
}

// scatter src ids into csr using LDS cursors (no global atomics)
__global__ __launch_bounds__(1024) void k_csr_p(const int* __restrict__ src,
                                                const int* __restrict__ dst,
                                                const int* __restrict__ cur0,
                                                int* __restrict__ csr) {
    __shared__ int h[NPG];
    int b = blockIdx.x, g = b & 7, k = b >> 3;
    const int* u = cur0 + (size_t)(g * KCH + k) * NPG;
    for (int i = threadIdx.x; i < NPG; i += 1024) h[i] = u[i];
    __syncthreads();
    int base = g * ESH + k * CH;
    for (int i = threadIdx.x; i < CH; i += 1024) {
        int d = __builtin_nontemporal_load(dst + base + i) - g * NPG;
        int s = __builtin_nontemporal_load(src + base + i);
        int p = atomicAdd(&h[d], 1);                // LDS atomic
        csr[p] = s;
    }
}

// fused: compose orig->stage3 map; chain stage3->orig selection
__global__ void k_composechain(int* __restrict__ m1, const int* __restrict__ m2,
                               const int* __restrict__ s2, const int* __restrict__ s1,
                               int* __restrict__ soc, int n1, int n2) {
    int i = blockIdx.x * blockDim.x + threadIdx.x;
    if (i < n2) soc[i] = s1[s2[i]];
    if (i < n1) { int a = m1[i]; m1[i] = (a >= 0) ? m2[a] : -1; }
}

// stage-1 gather-aggregate bf16, graph->XCD swizzled.
// 16 lanes/node x uint4 (16B) loads, 8-deep MLP.
__global__ __launch_bounds__(256) void k_agg2b(unsigned short* __restrict__ IN,
                                               const int* __restrict__ rowstart,
                                               const int* __restrict__ csr, int npg) {
    int g = blockIdx.x & 7;
    int local = (blockIdx.x >> 3) * 16 + (threadIdx.x >> 4);
    int lane = threadIdx.x & 15;
    if (local >= npg) return;
    int i = g * npg + local;
    int b = rowstart[i], e = rowstart[i + 1];
    float a0 = 0, a1 = 0, a2 = 0, a3 = 0, a4 = 0, a5 = 0, a6 = 0, a7 = 0;
    int j = b;
    for (; j + 8 <= e; j += 8) {      // 8-way MLP
        int sx[8];
#pragma unroll
        for (int t = 0; t < 8; t++) sx[t] = __builtin_nontemporal_load(csr + j + t);
        uint4 ux[8];
#pragma unroll
        for (int t = 0; t < 8; t++)
            ux[t] = *(const uint4*)(IN + (size_t)sx[t] * 256 + 128 + lane * 8);
#pragma unroll
        for (int t = 0; t < 8; t++) {
            a0 += blo(ux[t].x); a1 += bhi(ux[t].x);
            a2 += blo(ux[t].y); a3 += bhi(ux[t].y);
            a4 += blo(ux[t].z); a5 += bhi(ux[t].z);
            a6 += blo(ux[t].w); a7 += bhi(ux[t].w);
        }
    }
    for (; j < e; j++) {
        int s0 = __builtin_nontemporal_load(csr + j);
        uint4 u = *(const uint4*)(IN + (size_t)s0 * 256 + 128 + lane * 8);
        a0 += blo(u.x); a1 += bhi(u.x);
        a2 += blo(u.y); a3 += bhi(u.y);
        a4 += blo(u.z); a5 += bhi(u.z);
        a6 += blo(u.w); a7 += bhi(u.w);
    }
    float rd = 1.0f / fmaxf((float)(e - b), 1.0f);
    short8 o;
    o[0] = (short)f2b(a0 * rd); o[1] = (short)f2b(a1 * rd);
    o[2] = (short)f2b(a2 * rd); o[3] = (short)f2b(a3 * rd);
    o[4] = (short)f2b(a4 * rd); o[5] = (short)f2b(a5 * rd);
    o[6] = (short)f2b(a6 * rd); o[7] = (short)f2b(a7 * rd);
    *(short8*)(IN + (size_t)i * 256 + lane * 8) = o;
}

// stages 2-3: pull over ORIGINAL neighbors of orig(i), predicated on map
__global__ __launch_bounds__(256) void k_agg2m(unsigned short* __restrict__ IN,
                                               const int* __restrict__ rowstart,
                                               const int* __restrict__ csr,
                                               const int* __restrict__ map,
                                               const int* __restrict__ orig_of, int npg) {
    int g = blockIdx.x & 7;
    int local = (blockIdx.x >> 3) * 16 + (threadIdx.x >> 4);
    int lane = threadIdx.x & 15;
    if (local >= npg) return;
    int i = g * npg + local;
    int o = orig_of[i];
    int b = rowstart[o], e = rowstart[o + 1];
    float a0 = 0, a1 = 0, a2 = 0, a3 = 0, a4 = 0, a5 = 0, a6 = 0, a7 = 0;
    int d = 0;
    int j = b;
    for (; j + 4 <= e; j += 4) {
        int c0 = __builtin_nontemporal_load(csr + j);
        int c1 = __builtin_nontemporal_load(csr + j + 1);
        int c2 = __builtin_nontemporal_load(csr + j + 2);
        int c3 = __builtin_nontemporal_load(csr + j + 3);
        int m0 = map[c0], m1 = map[c1], m2 = map[c2], m3 = map[c3];
#pragma unroll
        for (int t = 0; t < 4; t++) {
            int s = (t == 0) ? m0 : (t == 1) ? m1 : (t == 2) ? m2 : m3;
            if (s >= 0) {
                uint4 u = *(const uint4*)(IN + (size_t)s * 256 + 128 + lane * 8);
                a0 += blo(u.x); a1 += bhi(u.x);
                a2 += blo(u.y); a3 += bhi(u.y);
                a4 += blo(u.z); a5 += bhi(u.z);
                a6 += blo(u.w); a7 += bhi(u.w);
                d++;
            }
        }
    }
    for (; j < e; j++) {
        int c0 = __builtin_nontemporal_load(csr + j);
        int s0 = map[c0];
        if (s0 >= 0) {
            uint4 u = *(const uint4*)(IN + (size_t)s0 * 256 + 128 + lane * 8);
            a0 += blo(u.x); a1 += bhi(u.x);
            a2 += blo(u.y); a3 += bhi(u.y);
            a4 += blo(u.z); a5 += bhi(u.z);
            a6 += blo(u.w); a7 += bhi(u.w);
            d++;
        }
    }
    float rd = 1.0f / fmaxf((float)d, 1.0f);
    short8 out;
    out[0] = (short)f2b(a0 * rd); out[1] = (short)f2b(a1 * rd);
    out[2] = (short)f2b(a2 * rd); out[3] = (short)f2b(a3 * rd);
    out[4] = (short)f2b(a4 * rd); out[5] = (short)f2b(a5 * rd);
    out[6] = (short)f2b(a6 * rd); out[7] = (short)f2b(a7 * rd);
    *(short8*)(IN + (size_t)i * 256 + lane * 8) = out;
}

// MFMA SAGE + fused scores. Direct-global A fragments, 128 rows/block,
// 2 row-tiles per wave, graph->XCD swizzle (bid&7 == graph).
// Epilogue stages h in bf16 LDS (17408B, was 33792B f32) -> 2x blocks/CU.
__global__ __launch_bounds__(256) void k_sage_b(
    const unsigned short* __restrict__ IN, const unsigned short* __restrict__ Wcat,
    const float* __restrict__ bias, const float* __restrict__ poolw,
    const float* __restrict__ normv,
    unsigned short* __restrict__ hb, float* __restrict__ sc,
    unsigned* __restrict__ key, int npg, int relu) {
    __shared__ unsigned short eps[64][136];     // 272B rows (16B-aligned)
    int tid = threadIdx.x;
    int wid = tid >> 6, lane = tid & 63;
    int q = lane >> 4, l15 = lane & 15;
    int g = blockIdx.x & 7, lb = blockIdx.x >> 3;
    int gbase = g * npg;
    int rowloc0 = lb * 128 + wid * 32;          // wave's tile0 local row

    floatx4 acc0[8], acc1[8];
#pragma unroll
    for (int c = 0; c < 8; c++) {
        acc0[c] = (floatx4){0.f, 0.f, 0.f, 0.f};
        acc1[c] = (floatx4){0.f, 0.f, 0.f, 0.f};
    }

    const unsigned short* bbase = Wcat + (size_t)l15 * 256 + q * 8;
    int lr0 = min(rowloc0 + l15, npg - 1);
    int lr1 = min(rowloc0 + 16 + l15, npg - 1);
    const unsigned short* a0p = IN + (size_t)(gbase + lr0) * 256 + q * 8;
    const unsigned short* a1p = IN + (size_t)(gbase + lr1) * 256 + q * 8;
#pragma unroll
    for (int ks = 0; ks < 8; ks++) {
        short8 a0 = *(const short8*)(a0p + (ks << 5));
        short8 a1 = *(const short8*)(a1p + (ks << 5));
#pragma unroll
        for (int c = 0; c < 8; c++) {
            short8 b = *(const short8*)(bbase + (c << 12) + (ks << 5));
            acc0[c] = __builtin_amdgcn_mfma_f32_16x16x32_bf16(a0, b, acc0[c], 0, 0, 0);
            acc1[c] = __builtin_amdgcn_mfma_f32_16x16x32_bf16(a1, b, acc1[c], 0, 0, 0);
        }
    }

    float invn = 1.0f / (*normv);
#pragma unroll
    for (int t = 0; t < 2; t++) {
        float p0 = 0, p1 = 0, p2 = 0, p3 = 0;
#pragma unroll
        for (int c = 0; c < 8; c++) {
            int col = (c << 4) + l15;
            float bv = bias[col];
            float wv = poolw[col];
            floatx4 v = (t == 0) ? acc0[c] : acc1[c];
            v[0] += bv; v[1] += bv; v[2] += bv; v[3] += bv;
            if (relu) {
                v[0] = fmaxf(v[0], 0.f); v[1] = fmaxf(v[1], 0.f);
                v[2] = fmaxf(v[2], 0.f); v[3] = fmaxf(v[3], 0.f);
            }
            p0 += v[0] * wv; p1 += v[1] * wv; p2 += v[2] * wv; p3 += v[3] * wv;
            int lr = wid * 16 + q * 4;
            eps[lr + 0][col] = f2b(v[0]);
            eps[lr + 1][col] = f2b(v[1]);
            eps[lr + 2][col] = f2b(v[2]);
            eps[lr + 3][col] = f2b(v[3]);
        }
#pragma unroll
        for (int off = 1; off < 16; off <<= 1) {
            p0 += __shfl_xor(p0, off);
            p1 += __shfl_xor(p1, off);
            p2 += __shfl_xor(p2, off);
            p3 += __shfl_xor(p3, off);
        }
        if (l15 == 0) {
            float ps[4] = {p0, p1, p2, p3};
#pragma unroll
            for (int j = 0; j < 4; j++) {
                int lrow = rowloc0 + t * 16 + q * 4 + j;
                if (lrow < npg) {
                    float s = tanhf(ps[j] * invn);
                    sc[gbase + lrow] = s;
                    key[gbase + lrow] = f2key(s);
                }
            }
        }
        __syncthreads();
        // store 64 rows: eps row r -> local row lb*128 + (r>>4)*32 + t*16 + (r&15)
#pragma unroll
        for (int it = 0; it < 4; it++) {
            int task = it * 256 + tid;
            int r = task >> 4, grp = task & 15;
            int lrow = lb * 128 + (r >> 4) * 32 + t * 16 + (r & 15);
            if (lrow < npg) {
                short8 u = *(const short8*)&eps[r][grp * 8];
                *(short8*)(hb + (size_t)(gbase + lrow) * 128 + grp * 8) = u;
            }
        }
        __syncthreads();
    }
}

// merged per-graph top-k: radix select then deterministic compaction
__global__ __launch_bounds__(1024) void k_topk(
    const unsigned* __restrict__ keys, const float* __restrict__ sc,
    int n_per, int k,
    int* __restrict__ node_map, int* __restrict__ sel_old, float* __restrict__ vals) {
    int g = blockIdx.x, tid = threadIdx.x;
    int lane = tid & 63, wid = tid >> 6;      // 16 waves
    const unsigned* kk = keys + (size_t)g * n_per;
    const float* ss = sc + (size_t)g * n_per;
    __shared__ int hist[256];
    __shared__ int suf[256];
    __shared__ unsigned sprefix;
    __shared__ int sr, sfound;
    __shared__ int we2[16], ws2[16];
    __shared__ int carry_pos, carry_eq;
    if (tid == 0) { sprefix = 0; sr = k; carry_pos = 0; carry_eq = 0; }
    __syncthreads();

    for (int b = 3; b >= 0; b--) {
        if (tid < 256) hist[tid] = 0;
        __syncthreads();
        unsigned pfx = sprefix;
        unsigned maskhi = (b == 3) ? 0u : (0xFFFFFFFFu << ((b + 1) * 8));
        for (int i = tid * 4; i < n_per; i += 4096) {
            uint4 kv4 = *(const uint4*)(kk + i);
#pragma unroll
            for (int j = 0; j < 4; j++) {
                unsigned kv = (j == 0) ? kv4.x : (j == 1) ? kv4.y : (j == 2) ? kv4.z : kv4.w;
                if ((kv & maskhi) == (pfx & maskhi))
                    atomicAdd(&hist[(kv >> (b * 8)) & 255], 1);
            }
        }
        __syncthreads();
        if (tid < 256) suf[tid] = hist[tid];
        __syncthreads();
        for (int off = 1; off < 256; off <<= 1) {
            int t = 0;
            if (tid < 256) t = suf[tid] + ((tid + off < 256) ? suf[tid + off] : 0);
            __syncthreads();
            if (tid < 256) suf[tid] = t;
            __syncthreads();
        }
        int r = sr;
        if (tid < 256) {
            int hi = (tid == 255) ? 0 : suf[tid + 1];
            if (hi < r && suf[tid] >= r) sfound = tid;   // unique
        }
        __syncthreads();
        if (tid == 0) {
            int v = sfound;
            int hi = (v == 255) ? 0 : suf[v + 1];
            sr = r - hi;
            sprefix = pfx | ((unsigned)v << (b * 8));
        }
        __syncthreads();
    }
    unsigned K = sprefix;
    int need = sr;
    __syncthreads();

    int nch = (n_per + 1023) >> 10;
    for (int ch = 0; ch < nch; ch++) {
        int i = (ch << 10) + tid;
        int valid = (i < n_per);
        unsigned kv = valid ? kk[i] : 0u;
        int is_gt = valid && (kv > K);
        int is_eq = valid && (kv == K);
        int e_incl = is_eq;
#pragma unroll
        for (int off = 1; off < 64; off <<= 1) {
            int t = __shfl_up(e_incl, off);
            e_incl += (lane >= off) ? t : 0;
        }
        if (lane == 63) we2[wid] = e_incl;
        __syncthreads();
        if (tid < 16) {
            int v = we2[tid];
#pragma unroll
            for (int off = 1; off < 16; off <<= 1) {
                int t = __shfl_up(v, off);
                v += ((int)tid >= off) ? t : 0;
            }
            we2[tid] = v;
        }
        __syncthreads();
        int eq_before = carry_eq + (e_incl - is_eq) + (wid ? we2[wid - 1] : 0);
        int sel = is_gt || (is_eq && eq_before < need);
        int s_incl = sel;
#pragma unroll
        for (int off = 1; off < 64; off <<= 1) {
            int t = __shfl_up(s_incl, off);
            s_incl += (lane >= off) ? t : 0;
        }
        if (lane == 63) ws2[wid] = s_incl;
        __syncthreads();
        if (tid < 16) {
            int v = ws2[tid];
#pragma unroll
            for (int off = 1; off < 16; off <<= 1) {
                int t = __shfl_up(v, off);
                v += ((int)tid >= off) ? t : 0;
            }
            ws2[tid] = v;
        }
        __syncthreads();
        int pos = carry_pos + (s_incl - sel) + (wid ? ws2[wid - 1] : 0);
        if (valid) {
            if (sel) {
                int ni = g * k + pos;
                node_map[(size_t)g * n_per + i] = ni;
                sel_old[ni] = g * n_per + i;
                vals[ni] = ss[i];
            } else {
                node_map[(size_t)g * n_per + i] = -1;
            }
        }
        __syncthreads();
        if (tid == 0) { carry_pos += ws2[15]; carry_eq += we2[15]; }
        __syncthreads();
    }
}

// gather selected h rows, scale by score, write bf16 into next IN x-half
__global__ void k_gatherb(const unsigned short* __restrict__ hb,
                          const int* __restrict__ sel_old,
                          const float* __restrict__ vals,
                          unsigned short* __restrict__ INnext, int m) {
    long t = blockIdx.x * (long)blockDim.x + threadIdx.x;
    int i = (int)(t >> 4), lane = (int)(t & 15);
    if (i >= m) return;
    int oi = sel_old[i];
    float v = vals[i];
    uint4 u = *(const uint4*)(hb + (size_t)oi * 128 + lane * 8);
    short8 o;
    o[0] = (short)f2b(blo(u.x) * v); o[1] = (short)f2b(bhi(u.x) * v);
    o[2] = (short)f2b(blo(u.y) * v); o[3] = (short)f2b(bhi(u.y) * v);
    o[4] = (short)f2b(blo(u.z) * v); o[5] = (short)f2b(bhi(u.z) * v);
    o[6] = (short)f2b(blo(u.w) * v); o[7] = (short)f2b(bhi(u.w) * v);
    *(short8*)(INnext + (size_t)i * 256 + 128 + lane * 8) = o;
}

// summarize partials: B*PSPLIT wave-blocks, lane = 2 features (ushort2)
__global__ __launch_bounds__(64) void k_partial2(const unsigned short* __restrict__ IN,
                                                 int k, float* __restrict__ part) {
    int g = blockIdx.x >> 8, s = blockIdx.x & (PSPLIT - 1);
    int lane = threadIdx.x;               // 64 lanes x ushort2 = 128 feats
    int rows = (k + PSPLIT - 1) / PSPLIT;
    int r0 = s * rows, r1 = min(k, r0 + rows);
    float s0 = 0, s1 = 0, m0 = -INFINITY, m1 = -INFINITY;
    for (int r = r0; r < r1; r++) {
        ushort2 u = *(const ushort2*)(IN + (size_t)(g * k + r) * 256 + 128 + lane * 2);
        float v0 = b2f(u.x), v1 = b2f(u.y);
        s0 += v0; s1 += v1;
        m0 = fmaxf(m0, v0); m1 = fmaxf(m1, v1);
    }
    size_t base = ((size_t)(g * PSPLIT + s) * 2) * F;
    *(float2*)&part[base + lane * 2] = make_float2(s0, s1);
    *(float2*)&part[base + F + lane * 2] = make_float2(m0, m1);
}

__global__ __launch_bounds__(256) void k_sumreduce2(const float* __restrict__ part, int k,
                                                    float* __restrict__ summary, int accum) {
    int g = blockIdx.x;
    int half = threadIdx.x >> 7, f = threadIdx.x & 127;  // 0=sum 1=max
    float sum = 0.0f, mx = -INFINITY;
    for (int s = 0; s < PSPLIT; s++) {
        float v = part[((size_t)(g * PSPLIT + s) * 2 + half) * F + f];
        sum += v;
        mx = fmaxf(mx, v);
    }
    float res = half ? mx : (sum / (float)k);
    int idx = g * 2 * F + half * F + f;
    if (accum) summary[idx] += res; else summary[idx] = res;
}

__global__ void k_out(const float* __restrict__ summary, const float* __restrict__ W,
                      const float* __restrict__ bias, float* __restrict__ out) {
    int g = blockIdx.x, j = threadIdx.x;  // 8 blocks x 64 threads
    float acc = bias[j];
    for (int t = 0; t < 2 * F; t++) acc += summary[g * 2 * F + t] * W[j * 2 * F + t];
    out[g * OUTD + j] = acc;
}

// ---------------- host launch ----------------
static inline int cdiv(long a, long b) { return (int)((a + b - 1) / b); }

extern "C" void kernel_launch(void* const* d_in, const int* in_sizes, int n_in,
                              void* d_out, int out_size, void* d_ws, size_t ws_size,
                              hipStream_t stream) {
    const float* x_in = (const float*)d_in[0];
    const int* ei     = (const int*)d_in[1];    // [2, E] -> src = ei, dst = ei+E
    const float* w1lW = (const float*)d_in[2];
    const float* w1lb = (const float*)d_in[3];
    const float* w1rW = (const float*)d_in[4];
    const float* p1w  = (const float*)d_in[5];
    const float* w2lW = (const float*)d_in[6];
    const float* w2lb = (const float*)d_in[7];
    const float* w2rW = (const float*)d_in[8];
    const float* p2w  = (const float*)d_in[9];
    const float* w3lW = (const float*)d_in[10];
    const float* w3lb = (const float*)d_in[11];
    const float* w3rW = (const float*)d_in[12];
    const float* p3w  = (const float*)d_in[13];
    const float* outW = (const float*)d_in[14];
    const float* outb = (const float*)d_in[15];
    float* out = (float*)d_out;

    float* ws = (float*)d_ws;
    unsigned short* INb  = (unsigned short*)(ws + OFF_IN);
    unsigned short* hb   = (unsigned short*)(ws + OFF_HB);
    // cnt/cur0 alias hb: consumed (csr build) before sage writes hb
    int* cnt     = (int*)(ws + OFF_HB);
    int* cur0    = cnt + (size_t)B * KCH * NPG;   // 2.56M ints each; 5.12M = SZ_HB
    float* sc    = ws + OFF_SC;
    unsigned* key = (unsigned*)(ws + OFF_KEY);
    int* nmap1   = (int*)(ws + OFF_MAP);
    int* nmap2   = (int*)(ws + OFF_MAP2);
    int* selo1   = (int*)(ws + OFF_SEL1);
    int* selo2   = (int*)(ws + OFF_SEL2);
    int* selo3   = (int*)(ws + OFF_SEL3);
    int* soc     = (int*)(ws + OFF_SOC);
    float* vals  = ws + OFF_VAL;
    int* csr     = (int*)(ws + OFF_CSR);
    int* hsum    = (int*)(ws + OFF_HSUM);
    int* incl    = (int*)(ws + OFF_INCL);
    int* bsum    = (int*)(ws + OFF_BSUM);
    int* rs      = (int*)(ws + OFF_RS);
    float* part    = ws + OFF_PART;
    float* summary = ws + OFF_SUM;
    unsigned short* wcat = (unsigned short*)(ws + OFF_WCAT);
    int* misc_i  = (int*)(ws + OFF_MISC);
    float* normv = (float*)(misc_i + 20);

    const int* esrc = ei;
    const int* edst = ei + E;

    // ================= stage 1 =================
    {
        int n = N0, nb = cdiv(n, 256);
        k_prep3<<<97, 256, 0, stream>>>(w1lW, w1rW, w2lW, w2rW, w3lW, w3rW,
                                        p1w, p2w, p3w, wcat, normv);
        k_cvt<<<cdiv((long)n * 32, 256), 256, 0, stream>>>(x_in, INb, n);
        k_hist_p<<<B * KCH, 1024, 0, stream>>>(edst, cnt);
        k_scan1c<<<nb, 256, 0, stream>>>(cnt, n, hsum, incl, bsum);
        k_scan3c<<<nb, 256, 0, stream>>>(hsum, incl, bsum, cnt, rs, cur0);
        k_csr_p<<<B * KCH, 1024, 0, stream>>>(esrc, edst, cur0, csr);
        k_agg2b<<<8 * cdiv(NPG, 16), 256, 0, stream>>>(INb, rs, csr, NPG);
        k_sage_b<<<8 * cdiv(NPG, 128), 256, 0, stream>>>(INb, wcat, w1lb, p1w, normv,
                                                         hb, sc, key, NPG, 0);
        k_topk<<<B, 1024, 0, stream>>>(key, sc, NPG, K1, nmap1, selo1, vals);
        k_gatherb<<<cdiv((long)N1 * 16, 256), 256, 0, stream>>>(hb, selo1, vals, INb, N1);
        k_partial2<<<B * PSPLIT, 64, 0, stream>>>(INb, K1, part);
        k_sumreduce2<<<B, 256, 0, stream>>>(part, K1, summary, 0);
    }

    // ================= stage 2 (stage-1 CSR + nmap1 predicate) =================
    {
        k_agg2m<<<8 * cdiv(K1, 16), 256, 0, stream>>>(INb, rs, csr, nmap1, selo1, K1);
        k_sage_b<<<8 * cdiv(K1, 128), 256, 0, stream>>>(INb, wcat + 32768, w2lb, p2w, normv + 1,
                                                        hb, sc, key, K1, 1);
        k_topk<<<B, 1024, 0, stream>>>(key, sc, K1, K2, nmap2, selo2, vals);
        k_gatherb<<<cdiv((long)N2 * 16, 256), 256, 0, stream>>>(hb, selo2, vals, INb, N2);
        k_partial2<<<B * PSPLIT, 64, 0, stream>>>(INb, K2, part);
        k_sumreduce2<<<B, 256, 0, stream>>>(part, K2, summary, 1);
        k_composechain<<<cdiv(N0, 256), 256, 0, stream>>>(nmap1, nmap2, selo2, selo1, soc, N0, N2);
    }

    // ================= stage 3 (stage-1 CSR + composed map) =================
    {
        k_agg2m<<<8 * cdiv(K2, 16), 256, 0, stream>>>(INb, rs, csr, nmap1, soc, K2);
        k_sage_b<<<8 * cdiv(K2, 128), 256, 0, stream>>>(INb, wcat + 65536, w3lb, p3w, normv + 2,
                                                        hb, sc, key, K2, 0);
        k_topk<<<B, 1024, 0, stream>>>(key, sc, K2, K3, nmap2, selo3, vals);
        k_gatherb<<<cdiv((long)N3 * 16, 256), 256, 0, stream>>>(hb, selo3, vals, INb, N3);
        k_partial2<<<B * PSPLIT, 64, 0, stream>>>(INb, K3, part);
        k_sumreduce2<<<B, 256, 0, stream>>>(part, K3, summary, 1);
    }

    // ================= output =================
    k_out<<<B, OUTD, 0, stream>>>(summary, outW, outb, out);
}

// Round 16
// 360.484 us; speedup vs baseline: 1.3236x; 1.0026x over previous
//
#include <hip/hip_runtime.h>
#include <hip/hip_bf16.h>
#include <math.h>

// ---------------- problem constants ----------------
constexpr int B    = 8;
constexpr int NPG  = 10000;           // nodes per graph (stage 1)
constexpr int F    = 128;             // feature dim (F_IN == H == 128)
constexpr int OUTD = 64;
constexpr int E    = B * NPG * 16;    // 1,280,000 edges
constexpr int N0   = B * NPG;         // 80000
constexpr int K1   = 5000, K2 = 2500, K3 = 1250;
constexpr int N1   = B * K1;          // 40000
constexpr int N2   = B * K2;          // 20000
constexpr int N3   = B * K3;          // 10000
constexpr int PSPLIT = 256;           // summarize row-split (per graph)
constexpr int ESH  = E / 8;           // 160000 edges per graph (edge list graph-contiguous)
constexpr int KCH  = 32;              // chunks per graph for CSR build (8g x 32 = 256 blocks)
constexpr int CH   = ESH / KCH;       // 5000 edges per chunk

// ---------------- ws layout (float units) ----------------
constexpr size_t OFF_IN   = 0;                           // [80000][256] bf16 (mean|x)
constexpr size_t SZ_IN    = (size_t)N0 * 256 / 2;
constexpr size_t OFF_HB   = OFF_IN + SZ_IN;              // h bf16 [80000][128]
constexpr size_t SZ_HB    = (size_t)N0 * F / 2;          // 5.12M floats
// cnt/cur0 ([256][NPG] ints each, 5.12M total) ALIAS the hb region: they are
// fully consumed (k_csr_p / k_scan3c) before k_sage_b writes hb.
constexpr size_t OFF_SC   = OFF_HB + SZ_HB;              // 80000 f32
constexpr size_t OFF_KEY  = OFF_SC + N0;                 // 80000 u32 (16B-aligned)
constexpr size_t OFF_MAP  = OFF_KEY + N0;                // 80000 i32 (nmap1 -> composed)
constexpr size_t OFF_MAP2 = OFF_MAP + N0;                // 40000 i32
constexpr size_t OFF_SEL1 = OFF_MAP2 + N1;               // 40000 i32 stage2->orig
constexpr size_t OFF_SEL2 = OFF_SEL1 + N1;               // 20000 i32 stage3->stage2
constexpr size_t OFF_SEL3 = OFF_SEL2 + N2;               // 10000 i32 final->stage3
constexpr size_t OFF_SOC  = OFF_SEL3 + N3;               // 20000 i32 stage3->orig
constexpr size_t OFF_VAL  = OFF_SOC + N2;                // 40000 f32
constexpr size_t OFF_CSR  = OFF_VAL + N1;                // E i32
constexpr size_t OFF_HSUM = OFF_CSR + E;                 // N0 i32
constexpr size_t OFF_INCL = OFF_HSUM + N0;               // N0 i32
constexpr size_t OFF_BSUM = OFF_INCL + N0;               // 512 i32
constexpr size_t OFF_RS   = OFF_BSUM + 512;              // N0+1 i32 (+pad)
constexpr size_t OFF_PART = OFF_RS + N0 + 64;            // B*PSPLIT*2*128 f32
constexpr size_t OFF_SUM  = OFF_PART + (size_t)B * PSPLIT * 2 * F;
constexpr size_t OFF_WCAT = OFF_SUM + (size_t)B * 2 * F; // 3 x [128][256] bf16
constexpr size_t OFF_MISC = OFF_WCAT + 3 * 128 * 256 / 2;

typedef __attribute__((ext_vector_type(8))) short short8;
typedef __attribute__((ext_vector_type(4))) float floatx4;

// ---------------- helpers ----------------
__device__ inline unsigned f2key(float f) {
    unsigned u = __float_as_uint(f);
    return (u & 0x80000000u) ? ~u : (u | 0x80000000u);
}
__device__ inline unsigned short f2b(float f) {      // RNE f32->bf16
    unsigned u = __float_as_uint(f);
    return (unsigned short)((u + 0x7FFFu + ((u >> 16) & 1u)) >> 16);
}
__device__ inline float b2f(unsigned short u) {
    return __uint_as_float((unsigned)u << 16);
}
// dword holding 2 bf16 -> 2 floats (1 VALU each)
__device__ inline float blo(unsigned u) { return __uint_as_float(u << 16); }
__device__ inline float bhi(unsigned u) { return __uint_as_float(u & 0xFFFF0000u); }

// ---------------- kernels ----------------
// all 3 stages' Wcat (bf16 concat) + pool-w norms in one launch
__global__ void k_prep3(const float* __restrict__ Wl1, const float* __restrict__ Wr1,
                        const float* __restrict__ Wl2, const float* __restrict__ Wr2,
                        const float* __restrict__ Wl3, const float* __restrict__ Wr3,
                        const float* __restrict__ p1, const float* __restrict__ p2,
                        const float* __restrict__ p3,
                        unsigned short* __restrict__ wcat, float* __restrict__ normv) {
    int b = blockIdx.x;
    if (b == 96) {
        int t = threadIdx.x;
        int which = t >> 6, lane = t & 63;
        if (which < 3) {
            const float* pw = (which == 0) ? p1 : (which == 1) ? p2 : p3;
            float v = 0.0f;
            for (int j = lane; j < F; j += 64) { float a = pw[j]; v += a * a; }
            for (int o = 32; o > 0; o >>= 1) v += __shfl_down(v, o);
            if (lane == 0) normv[which] = sqrtf(v);
        }
        return;
    }
    int stage = b >> 5;
    const float* Wl = (stage == 0) ? Wl1 : (stage == 1) ? Wl2 : Wl3;
    const float* Wr = (stage == 0) ? Wr1 : (stage == 1) ? Wr2 : Wr3;
    unsigned short* W = wcat + (size_t)stage * 128 * 256;
    int idx = ((b & 31) * 256 + threadIdx.x) * 4;
    int o = idx >> 8, k = idx & 255;
    const float* p = (k < 128) ? (Wl + o * 128 + k) : (Wr + o * 128 + (k - 128));
    float4 v = *(const float4*)p;
    ushort4 u;
    u.x = f2b(v.x); u.y = f2b(v.y); u.z = f2b(v.z); u.w = f2b(v.w);
    *(ushort4*)(W + idx) = u;
}

// x f32 -> bf16 into IN slab x-half
__global__ void k_cvt(const float* __restrict__ x, unsigned short* __restrict__ IN, int n) {
    long t = blockIdx.x * (long)blockDim.x + threadIdx.x;
    int i = (int)(t >> 5), lane = (int)(t & 31);
    if (i >= n) return;
    float4 v = ((const float4*)(x + (size_t)i * F))[lane];
    ushort4 u;
    u.x = f2b(v.x); u.y = f2b(v.y); u.z = f2b(v.z); u.w = f2b(v.w);
    *(ushort4*)(IN + (size_t)i * 256 + 128 + lane * 4) = u;
}

// -------- atomic-free CSR build (stage 1), 256 blocks (1/CU) --------
__global__ __launch_bounds__(1024) void k_hist_p(const int* __restrict__ dst,
                                                 int* __restrict__ cnt) {
    __shared__ int h[NPG];
    int b = blockIdx.x, g = b & 7, k = b >> 3;
    for (int i = threadIdx.x; i < NPG; i += 1024) h[i] = 0;
    __syncthreads();
    int base = g * ESH + k * CH;
    for (int i = threadIdx.x; i < CH; i += 1024) {
        int d = __builtin_nontemporal_load(dst + base + i) - g * NPG;
        atomicAdd(&h[d], 1);                        // LDS atomic
    }
    __syncthreads();
    int* o = cnt + (size_t)(g * KCH + k) * NPG;
    for (int i = threadIdx.x; i < NPG; i += 1024) o[i] = h[i];
}

// fused sumcnt + scan1: hsum[i] = sum over chunks; block-inclusive scan
__global__ __launch_bounds__(256) void k_scan1c(const int* __restrict__ cnt, int n,
                                                int* __restrict__ hsum,
                                                int* __restrict__ incl, int* __restrict__ bsum) {
    __shared__ int s[256];
    int i = blockIdx.x * 256 + threadIdx.x;
    int v = 0;
    if (i < n) {
        int g = i / NPG, l = i - g * NPG;
        const int* c = cnt + (size_t)g * KCH * NPG + l;
#pragma unroll
        for (int k = 0; k < KCH; k++) v += c[(size_t)k * NPG];
        hsum[i] = v;
    }
    s[threadIdx.x] = v;
    __syncthreads();
    for (int off = 1; off < 256; off <<= 1) {
        int t = s[threadIdx.x] + ((threadIdx.x >= off) ? s[threadIdx.x - off] : 0);
        __syncthreads();
        s[threadIdx.x] = t;
        __syncthreads();
    }
    if (i < n) incl[i] = s[threadIdx.x];
    if (threadIdx.x == 255) bsum[blockIdx.x] = s[255];
}

// rowstart + per-chunk cursor bases; block computes its own bsum prefix
__global__ __launch_bounds__(256) void k_scan3c(const int* __restrict__ in,
                                                const int* __restrict__ incl,
                                                const int* __restrict__ bsum,
                                                const int* __restrict__ cnt,
                                                int* __restrict__ rowstart,
                                                int* __restrict__ cur0) {
    __shared__ int red[256];
    int acc = 0;
    for (int t = threadIdx.x; t < blockIdx.x; t += 256) acc += bsum[t];
    red[threadIdx.x] = acc;
    __syncthreads();
    for (int off = 128; off > 0; off >>= 1) {
        if (threadIdx.x < off) red[threadIdx.x] += red[threadIdx.x + off];
        __syncthreads();
    }
    int pref = red[0];
    int i = blockIdx.x * 256 + threadIdx.x;
    if (i >= N0) return;
    int ex = incl[i] - in[i] + pref;
    rowstart[i] = ex;
    if (i == N0 - 1) rowstart[N0] = ex + in[i];
    int g = i / NPG, l = i - g * NPG;
    const int* c = cnt + (size_t)g * KCH * NPG + l;
    int* u = cur0 + (size_t)g * KCH * NPG + l;
    int run = ex;
#pragma unroll
    for (int k = 0; k < KCH; k++) {
        u[(size_t)k * NPG] = run;
        run += c[(size_t)k * NPG];
    }
}

// scatter src ids into csr using LDS cursors (no global atomics)
__global__ __launch_bounds__(1024) void k_csr_p(const int* __restrict__ src,
                                                const int* __restrict__ dst,
                                                const int* __restrict__ cur0,
                                                int* __restrict__ csr) {
    __shared__ int h[NPG];
    int b = blockIdx.x, g = b & 7, k = b >> 3;
    const int* u = cur0 + (size_t)(g * KCH + k) * NPG;
    for (int i = threadIdx.x; i < NPG; i += 1024) h[i] = u[i];
    __syncthreads();
    int base = g * ESH + k * CH;
    for (int i = threadIdx.x; i < CH; i += 1024) {
        int d = __builtin_nontemporal_load(dst + base + i) - g * NPG;
        int s = __builtin_nontemporal_load(src + base + i);
        int p = atomicAdd(&h[d], 1);                // LDS atomic
        csr[p] = s;
    }
}

// fused: compose orig->stage3 map; chain stage3->orig selection
__global__ void k_composechain(int* __restrict__ m1, const int* __restrict__ m2,
                               const int* __restrict__ s2, const int* __restrict__ s1,
                               int* __restrict__ soc, int n1, int n2) {
    int i = blockIdx.x * blockDim.x + threadIdx.x;
    if (i < n2) soc[i] = s1[s2[i]];
    if (i < n1) { int a = m1[i]; m1[i] = (a >= 0) ? m2[a] : -1; }
}

// stage-1 gather-aggregate bf16, graph->XCD swizzled.
// 16 lanes/node x uint4 (16B) loads, 8-deep MLP.
__global__ __launch_bounds__(256) void k_agg2b(unsigned short* __restrict__ IN,
                                               const int* __restrict__ rowstart,
                                               const int* __restrict__ csr, int npg) {
    int g = blockIdx.x & 7;
    int local = (blockIdx.x >> 3) * 16 + (threadIdx.x >> 4);
    int lane = threadIdx.x & 15;
    if (local >= npg) return;
    int i = g * npg + local;
    int b = rowstart[i], e = rowstart[i + 1];
    float a0 = 0, a1 = 0, a2 = 0, a3 = 0, a4 = 0, a5 = 0, a6 = 0, a7 = 0;
    int j = b;
    for (; j + 8 <= e; j += 8) {      // 8-way MLP
        int sx[8];
#pragma unroll
        for (int t = 0; t < 8; t++) sx[t] = __builtin_nontemporal_load(csr + j + t);
        uint4 ux[8];
#pragma unroll
        for (int t = 0; t < 8; t++)
            ux[t] = *(const uint4*)(IN + (size_t)sx[t] * 256 + 128 + lane * 8);
#pragma unroll
        for (int t = 0; t < 8; t++) {
            a0 += blo(ux[t].x); a1 += bhi(ux[t].x);
            a2 += blo(ux[t].y); a3 += bhi(ux[t].y);
            a4 += blo(ux[t].z); a5 += bhi(ux[t].z);
            a6 += blo(ux[t].w); a7 += bhi(ux[t].w);
        }
    }
    for (; j < e; j++) {
        int s0 = __builtin_nontemporal_load(csr + j);
        uint4 u = *(const uint4*)(IN + (size_t)s0 * 256 + 128 + lane * 8);
        a0 += blo(u.x); a1 += bhi(u.x);
        a2 += blo(u.y); a3 += bhi(u.y);
        a4 += blo(u.z); a5 += bhi(u.z);
        a6 += blo(u.w); a7 += bhi(u.w);
    }
    float rd = 1.0f / fmaxf((float)(e - b), 1.0f);
    short8 o;
    o[0] = (short)f2b(a0 * rd); o[1] = (short)f2b(a1 * rd);
    o[2] = (short)f2b(a2 * rd); o[3] = (short)f2b(a3 * rd);
    o[4] = (short)f2b(a4 * rd); o[5] = (short)f2b(a5 * rd);
    o[6] = (short)f2b(a6 * rd); o[7] = (short)f2b(a7 * rd);
    *(short8*)(IN + (size_t)i * 256 + lane * 8) = o;
}

// stages 2-3: pull over ORIGINAL neighbors of orig(i), predicated on map
__global__ __launch_bounds__(256) void k_agg2m(unsigned short* __restrict__ IN,
                                               const int* __restrict__ rowstart,
                                               const int* __restrict__ csr,
                                               const int* __restrict__ map,
                                               const int* __restrict__ orig_of, int npg) {
    int g = blockIdx.x & 7;
    int local = (blockIdx.x >> 3) * 16 + (threadIdx.x >> 4);
    int lane = threadIdx.x & 15;
    if (local >= npg) return;
    int i = g * npg + local;
    int o = orig_of[i];
    int b = rowstart[o], e = rowstart[o + 1];
    float a0 = 0, a1 = 0, a2 = 0, a3 = 0, a4 = 0, a5 = 0, a6 = 0, a7 = 0;
    int d = 0;
    int j = b;
    for (; j + 4 <= e; j += 4) {
        int c0 = __builtin_nontemporal_load(csr + j);
        int c1 = __builtin_nontemporal_load(csr + j + 1);
        int c2 = __builtin_nontemporal_load(csr + j + 2);
        int c3 = __builtin_nontemporal_load(csr + j + 3);
        int m0 = map[c0], m1 = map[c1], m2 = map[c2], m3 = map[c3];
#pragma unroll
        for (int t = 0; t < 4; t++) {
            int s = (t == 0) ? m0 : (t == 1) ? m1 : (t == 2) ? m2 : m3;
            if (s >= 0) {
                uint4 u = *(const uint4*)(IN + (size_t)s * 256 + 128 + lane * 8);
                a0 += blo(u.x); a1 += bhi(u.x);
                a2 += blo(u.y); a3 += bhi(u.y);
                a4 += blo(u.z); a5 += bhi(u.z);
                a6 += blo(u.w); a7 += bhi(u.w);
                d++;
            }
        }
    }
    for (; j < e; j++) {
        int c0 = __builtin_nontemporal_load(csr + j);
        int s0 = map[c0];
        if (s0 >= 0) {
            uint4 u = *(const uint4*)(IN + (size_t)s0 * 256 + 128 + lane * 8);
            a0 += blo(u.x); a1 += bhi(u.x);
            a2 += blo(u.y); a3 += bhi(u.y);
            a4 += blo(u.z); a5 += bhi(u.z);
            a6 += blo(u.w); a7 += bhi(u.w);
            d++;
        }
    }
    float rd = 1.0f / fmaxf((float)d, 1.0f);
    short8 out;
    out[0] = (short)f2b(a0 * rd); out[1] = (short)f2b(a1 * rd);
    out[2] = (short)f2b(a2 * rd); out[3] = (short)f2b(a3 * rd);
    out[4] = (short)f2b(a4 * rd); out[5] = (short)f2b(a5 * rd);
    out[6] = (short)f2b(a6 * rd); out[7] = (short)f2b(a7 * rd);
    *(short8*)(IN + (size_t)i * 256 + lane * 8) = out;
}

// MFMA SAGE + fused scores. ALL 16 A-fragments preloaded to registers
// (16 independent loads in flight, then uninterrupted MFMA stream).
// 128 rows/block, 2 row-tiles per wave, graph->XCD swizzle.
__global__ __launch_bounds__(256) void k_sage_b(
    const unsigned short* __restrict__ IN, const unsigned short* __restrict__ Wcat,
    const float* __restrict__ bias, const float* __restrict__ poolw,
    const float* __restrict__ normv,
    unsigned short* __restrict__ hb, float* __restrict__ sc,
    unsigned* __restrict__ key, int npg, int relu) {
    __shared__ unsigned short eps[64][136];     // 272B rows (16B-aligned)
    int tid = threadIdx.x;
    int wid = tid >> 6, lane = tid & 63;
    int q = lane >> 4, l15 = lane & 15;
    int g = blockIdx.x & 7, lb = blockIdx.x >> 3;
    int gbase = g * npg;
    int rowloc0 = lb * 128 + wid * 32;          // wave's tile0 local row

    floatx4 acc0[8], acc1[8];
#pragma unroll
    for (int c = 0; c < 8; c++) {
        acc0[c] = (floatx4){0.f, 0.f, 0.f, 0.f};
        acc1[c] = (floatx4){0.f, 0.f, 0.f, 0.f};
    }

    const unsigned short* bbase = Wcat + (size_t)l15 * 256 + q * 8;
    int lr0 = min(rowloc0 + l15, npg - 1);
    int lr1 = min(rowloc0 + 16 + l15, npg - 1);
    const unsigned short* a0p = IN + (size_t)(gbase + lr0) * 256 + q * 8;
    const unsigned short* a1p = IN + (size_t)(gbase + lr1) * 256 + q * 8;

    // preload all A fragments (compile-time indices -> registers)
    short8 af0[8], af1[8];
#pragma unroll
    for (int ks = 0; ks < 8; ks++) {
        af0[ks] = *(const short8*)(a0p + (ks << 5));
        af1[ks] = *(const short8*)(a1p + (ks << 5));
    }
#pragma unroll
    for (int ks = 0; ks < 8; ks++) {
#pragma unroll
        for (int c = 0; c < 8; c++) {
            short8 b = *(const short8*)(bbase + (c << 12) + (ks << 5));
            acc0[c] = __builtin_amdgcn_mfma_f32_16x16x32_bf16(af0[ks], b, acc0[c], 0, 0, 0);
            acc1[c] = __builtin_amdgcn_mfma_f32_16x16x32_bf16(af1[ks], b, acc1[c], 0, 0, 0);
        }
    }

    float invn = 1.0f / (*normv);
#pragma unroll
    for (int t = 0; t < 2; t++) {
        float p0 = 0, p1 = 0, p2 = 0, p3 = 0;
#pragma unroll
        for (int c = 0; c < 8; c++) {
            int col = (c << 4) + l15;
            float bv = bias[col];
            float wv = poolw[col];
            floatx4 v = (t == 0) ? acc0[c] : acc1[c];
            v[0] += bv; v[1] += bv; v[2] += bv; v[3] += bv;
            if (relu) {
                v[0] = fmaxf(v[0], 0.f); v[1] = fmaxf(v[1], 0.f);
                v[2] = fmaxf(v[2], 0.f); v[3] = fmaxf(v[3], 0.f);
            }
            p0 += v[0] * wv; p1 += v[1] * wv; p2 += v[2] * wv; p3 += v[3] * wv;
            int lr = wid * 16 + q * 4;
            eps[lr + 0][col] = f2b(v[0]);
            eps[lr + 1][col] = f2b(v[1]);
            eps[lr + 2][col] = f2b(v[2]);
            eps[lr + 3][col] = f2b(v[3]);
        }
#pragma unroll
        for (int off = 1; off < 16; off <<= 1) {
            p0 += __shfl_xor(p0, off);
            p1 += __shfl_xor(p1, off);
            p2 += __shfl_xor(p2, off);
            p3 += __shfl_xor(p3, off);
        }
        if (l15 == 0) {
            float ps[4] = {p0, p1, p2, p3};
#pragma unroll
            for (int j = 0; j < 4; j++) {
                int lrow = rowloc0 + t * 16 + q * 4 + j;
                if (lrow < npg) {
                    float s = tanhf(ps[j] * invn);
                    sc[gbase + lrow] = s;
                    key[gbase + lrow] = f2key(s);
                }
            }
        }
        __syncthreads();
        // store 64 rows: eps row r -> local row lb*128 + (r>>4)*32 + t*16 + (r&15)
#pragma unroll
        for (int it = 0; it < 4; it++) {
            int task = it * 256 + tid;
            int r = task >> 4, grp = task & 15;
            int lrow = lb * 128 + (r >> 4) * 32 + t * 16 + (r & 15);
            if (lrow < npg) {
                short8 u = *(const short8*)&eps[r][grp * 8];
                *(short8*)(hb + (size_t)(gbase + lrow) * 128 + grp * 8) = u;
            }
        }
        __syncthreads();
    }
}

// merged per-graph top-k: radix select then deterministic compaction
__global__ __launch_bounds__(1024) void k_topk(
    const unsigned* __restrict__ keys, const float* __restrict__ sc,
    int n_per, int k,
    int* __restrict__ node_map, int* __restrict__ sel_old, float* __restrict__ vals) {
    int g = blockIdx.x, tid = threadIdx.x;
    int lane = tid & 63, wid = tid >> 6;      // 16 waves
    const unsigned* kk = keys + (size_t)g * n_per;
    const float* ss = sc + (size_t)g * n_per;
    __shared__ int hist[256];
    __shared__ int suf[256];
    __shared__ unsigned sprefix;
    __shared__ int sr, sfound;
    __shared__ int we2[16], ws2[16];
    __shared__ int carry_pos, carry_eq;
    if (tid == 0) { sprefix = 0; sr = k; carry_pos = 0; carry_eq = 0; }
    __syncthreads();

    for (int b = 3; b >= 0; b--) {
        if (tid < 256) hist[tid] = 0;
        __syncthreads();
        unsigned pfx = sprefix;
        unsigned maskhi = (b == 3) ? 0u : (0xFFFFFFFFu << ((b + 1) * 8));
        for (int i = tid * 4; i < n_per; i += 4096) {
            uint4 kv4 = *(const uint4*)(kk + i);
#pragma unroll
            for (int j = 0; j < 4; j++) {
                unsigned kv = (j == 0) ? kv4.x : (j == 1) ? kv4.y : (j == 2) ? kv4.z : kv4.w;
                if ((kv & maskhi) == (pfx & maskhi))
                    atomicAdd(&hist[(kv >> (b * 8)) & 255], 1);
            }
        }
        __syncthreads();
        if (tid < 256) suf[tid] = hist[tid];
        __syncthreads();
        for (int off = 1; off < 256; off <<= 1) {
            int t = 0;
            if (tid < 256) t = suf[tid] + ((tid + off < 256) ? suf[tid + off] : 0);
            __syncthreads();
            if (tid < 256) suf[tid] = t;
            __syncthreads();
        }
        int r = sr;
        if (tid < 256) {
            int hi = (tid == 255) ? 0 : suf[tid + 1];
            if (hi < r && suf[tid] >= r) sfound = tid;   // unique
        }
        __syncthreads();
        if (tid == 0) {
            int v = sfound;
            int hi = (v == 255) ? 0 : suf[v + 1];
            sr = r - hi;
            sprefix = pfx | ((unsigned)v << (b * 8));
        }
        __syncthreads();
    }
    unsigned K = sprefix;
    int need = sr;
    __syncthreads();

    int nch = (n_per + 1023) >> 10;
    for (int ch = 0; ch < nch; ch++) {
        int i = (ch << 10) + tid;
        int valid = (i < n_per);
        unsigned kv = valid ? kk[i] : 0u;
        int is_gt = valid && (kv > K);
        int is_eq = valid && (kv == K);
        int e_incl = is_eq;
#pragma unroll
        for (int off = 1; off < 64; off <<= 1) {
            int t = __shfl_up(e_incl, off);
            e_incl += (lane >= off) ? t : 0;
        }
        if (lane == 63) we2[wid] = e_incl;
        __syncthreads();
        if (tid < 16) {
            int v = we2[tid];
#pragma unroll
            for (int off = 1; off < 16; off <<= 1) {
                int t = __shfl_up(v, off);
                v += ((int)tid >= off) ? t : 0;
            }
            we2[tid] = v;
        }
        __syncthreads();
        int eq_before = carry_eq + (e_incl - is_eq) + (wid ? we2[wid - 1] : 0);
        int sel = is_gt || (is_eq && eq_before < need);
        int s_incl = sel;
#pragma unroll
        for (int off = 1; off < 64; off <<= 1) {
            int t = __shfl_up(s_incl, off);
            s_incl += (lane >= off) ? t : 0;
        }
        if (lane == 63) ws2[wid] = s_incl;
        __syncthreads();
        if (tid < 16) {
            int v = ws2[tid];
#pragma unroll
            for (int off = 1; off < 16; off <<= 1) {
                int t = __shfl_up(v, off);
                v += ((int)tid >= off) ? t : 0;
            }
            ws2[tid] = v;
        }
        __syncthreads();
        int pos = carry_pos + (s_incl - sel) + (wid ? ws2[wid - 1] : 0);
        if (valid) {
            if (sel) {
                int ni = g * k + pos;
                node_map[(size_t)g * n_per + i] = ni;
                sel_old[ni] = g * n_per + i;
                vals[ni] = ss[i];
            } else {
                node_map[(size_t)g * n_per + i] = -1;
            }
        }
        __syncthreads();
        if (tid == 0) { carry_pos += ws2[15]; carry_eq += we2[15]; }
        __syncthreads();
    }
}

// gather selected h rows, scale by score, write bf16 into next IN x-half
__global__ void k_gatherb(const unsigned short* __restrict__ hb,
                          const int* __restrict__ sel_old,
                          const float* __restrict__ vals,
                          unsigned short* __restrict__ INnext, int m) {
    long t = blockIdx.x * (long)blockDim.x + threadIdx.x;
    int i = (int)(t >> 4), lane = (int)(t & 15);
    if (i >= m) return;
    int oi = sel_old[i];
    float v = vals[i];
    uint4 u = *(const uint4*)(hb + (size_t)oi * 128 + lane * 8);
    short8 o;
    o[0] = (short)f2b(blo(u.x) * v); o[1] = (short)f2b(bhi(u.x) * v);
    o[2] = (short)f2b(blo(u.y) * v); o[3] = (short)f2b(bhi(u.y) * v);
    o[4] = (short)f2b(blo(u.z) * v); o[5] = (short)f2b(bhi(u.z) * v);
    o[6] = (short)f2b(blo(u.w) * v); o[7] = (short)f2b(bhi(u.w) * v);
    *(short8*)(INnext + (size_t)i * 256 + 128 + lane * 8) = o;
}

// summarize partials: B*PSPLIT wave-blocks, lane = 2 features (ushort2)
__global__ __launch_bounds__(64) void k_partial2(const unsigned short* __restrict__ IN,
                                                 int k, float* __restrict__ part) {
    int g = blockIdx.x >> 8, s = blockIdx.x & (PSPLIT - 1);
    int lane = threadIdx.x;               // 64 lanes x ushort2 = 128 feats
    int rows = (k + PSPLIT - 1) / PSPLIT;
    int r0 = s * rows, r1 = min(k, r0 + rows);
    float s0 = 0, s1 = 0, m0 = -INFINITY, m1 = -INFINITY;
    for (int r = r0; r < r1; r++) {
        ushort2 u = *(const ushort2*)(IN + (size_t)(g * k + r) * 256 + 128 + lane * 2);
        float v0 = b2f(u.x), v1 = b2f(u.y);
        s0 += v0; s1 += v1;
        m0 = fmaxf(m0, v0); m1 = fmaxf(m1, v1);
    }
    size_t base = ((size_t)(g * PSPLIT + s) * 2) * F;
    *(float2*)&part[base + lane * 2] = make_float2(s0, s1);
    *(float2*)&part[base + F + lane * 2] = make_float2(m0, m1);
}

__global__ __launch_bounds__(256) void k_sumreduce2(const float* __restrict__ part, int k,
                                                    float* __restrict__ summary, int accum) {
    int g = blockIdx.x;
    int half = threadIdx.x >> 7, f = threadIdx.x & 127;  // 0=sum 1=max
    float sum = 0.0f, mx = -INFINITY;
    for (int s = 0; s < PSPLIT; s++) {
        float v = part[((size_t)(g * PSPLIT + s) * 2 + half) * F + f];
        sum += v;
        mx = fmaxf(mx, v);
    }
    float res = half ? mx : (sum / (float)k);
    int idx = g * 2 * F + half * F + f;
    if (accum) summary[idx] += res; else summary[idx] = res;
}

__global__ void k_out(const float* __restrict__ summary, const float* __restrict__ W,
                      const float* __restrict__ bias, float* __restrict__ out) {
    int g = blockIdx.x, j = threadIdx.x;  // 8 blocks x 64 threads
    float acc = bias[j];
    for (int t = 0; t < 2 * F; t++) acc += summary[g * 2 * F + t] * W[j * 2 * F + t];
    out[g * OUTD + j] = acc;
}

// ---------------- host launch ----------------
static inline int cdiv(long a, long b) { return (int)((a + b - 1) / b); }

extern "C" void kernel_launch(void* const* d_in, const int* in_sizes, int n_in,
                              void* d_out, int out_size, void* d_ws, size_t ws_size,
                              hipStream_t stream) {
    const float* x_in = (const float*)d_in[0];
    const int* ei     = (const int*)d_in[1];    // [2, E] -> src = ei, dst = ei+E
    const float* w1lW = (const float*)d_in[2];
    const float* w1lb = (const float*)d_in[3];
    const float* w1rW = (const float*)d_in[4];
    const float* p1w  = (const float*)d_in[5];
    const float* w2lW = (const float*)d_in[6];
    const float* w2lb = (const float*)d_in[7];
    const float* w2rW = (const float*)d_in[8];
    const float* p2w  = (const float*)d_in[9];
    const float* w3lW = (const float*)d_in[10];
    const float* w3lb = (const float*)d_in[11];
    const float* w3rW = (const float*)d_in[12];
    const float* p3w  = (const float*)d_in[13];
    const float* outW = (const float*)d_in[14];
    const float* outb = (const float*)d_in[15];
    float* out = (float*)d_out;

    float* ws = (float*)d_ws;
    unsigned short* INb  = (unsigned short*)(ws + OFF_IN);
    unsigned short* hb   = (unsigned short*)(ws + OFF_HB);
    // cnt/cur0 alias hb: consumed (csr build) before sage writes hb
    int* cnt     = (int*)(ws + OFF_HB);
    int* cur0    = cnt + (size_t)B * KCH * NPG;   // 2.56M ints each; 5.12M = SZ_HB
    float* sc    = ws + OFF_SC;
    unsigned* key = (unsigned*)(ws + OFF_KEY);
    int* nmap1   = (int*)(ws + OFF_MAP);
    int* nmap2   = (int*)(ws + OFF_MAP2);
    int* selo1   = (int*)(ws + OFF_SEL1);
    int* selo2   = (int*)(ws + OFF_SEL2);
    int* selo3   = (int*)(ws + OFF_SEL3);
    int* soc     = (int*)(ws + OFF_SOC);
    float* vals  = ws + OFF_VAL;
    int* csr     = (int*)(ws + OFF_CSR);
    int* hsum    = (int*)(ws + OFF_HSUM);
    int* incl    = (int*)(ws + OFF_INCL);
    int* bsum    = (int*)(ws + OFF_BSUM);
    int* rs      = (int*)(ws + OFF_RS);
    float* part    = ws + OFF_PART;
    float* summary = ws + OFF_SUM;
    unsigned short* wcat = (unsigned short*)(ws + OFF_WCAT);
    int* misc_i  = (int*)(ws + OFF_MISC);
    float* normv = (float*)(misc_i + 20);

    const int* esrc = ei;
    const int* edst = ei + E;

    // ================= stage 1 =================
    {
        int n = N0, nb = cdiv(n, 256);
        k_prep3<<<97, 256, 0, stream>>>(w1lW, w1rW, w2lW, w2rW, w3lW, w3rW,
                                        p1w, p2w, p3w, wcat, normv);
        k_cvt<<<cdiv((long)n * 32, 256), 256, 0, stream>>>(x_in, INb, n);
        k_hist_p<<<B * KCH, 1024, 0, stream>>>(edst, cnt);
        k_scan1c<<<nb, 256, 0, stream>>>(cnt, n, hsum, incl, bsum);
        k_scan3c<<<nb, 256, 0, stream>>>(hsum, incl, bsum, cnt, rs, cur0);
        k_csr_p<<<B * KCH, 1024, 0, stream>>>(esrc, edst, cur0, csr);
        k_agg2b<<<8 * cdiv(NPG, 16), 256, 0, stream>>>(INb, rs, csr, NPG);
        k_sage_b<<<8 * cdiv(NPG, 128), 256, 0, stream>>>(INb, wcat, w1lb, p1w, normv,
                                                         hb, sc, key, NPG, 0);
        k_topk<<<B, 1024, 0, stream>>>(key, sc, NPG, K1, nmap1, selo1, vals);
        k_gatherb<<<cdiv((long)N1 * 16, 256), 256, 0, stream>>>(hb, selo1, vals, INb, N1);
        k_partial2<<<B * PSPLIT, 64, 0, stream>>>(INb, K1, part);
        k_sumreduce2<<<B, 256, 0, stream>>>(part, K1, summary, 0);
    }

    // ================= stage 2 (stage-1 CSR + nmap1 predicate) =================
    {
        k_agg2m<<<8 * cdiv(K1, 16), 256, 0, stream>>>(INb, rs, csr, nmap1, selo1, K1);
        k_sage_b<<<8 * cdiv(K1, 128), 256, 0, stream>>>(INb, wcat + 32768, w2lb, p2w, normv + 1,
                                                        hb, sc, key, K1, 1);
        k_topk<<<B, 1024, 0, stream>>>(key, sc, K1, K2, nmap2, selo2, vals);
        k_gatherb<<<cdiv((long)N2 * 16, 256), 256, 0, stream>>>(hb, selo2, vals, INb, N2);
        k_partial2<<<B * PSPLIT, 64, 0, stream>>>(INb, K2, part);
        k_sumreduce2<<<B, 256, 0, stream>>>(part, K2, summary, 1);
        k_composechain<<<cdiv(N0, 256), 256, 0, stream>>>(nmap1, nmap2, selo2, selo1, soc, N0, N2);
    }

    // ================= stage 3 (stage-1 CSR + composed map) =================
    {
        k_agg2m<<<8 * cdiv(K2, 16), 256, 0, stream>>>(INb, rs, csr, nmap1, soc, K2);
        k_sage_b<<<8 * cdiv(K2, 128), 256, 0, stream>>>(INb, wcat + 65536, w3lb, p3w, normv + 2,
                                                        hb, sc, key, K2, 0);
        k_topk<<<B, 1024, 0, stream>>>(key, sc, K2, K3, nmap2, selo3, vals);
        k_gatherb<<<cdiv((long)N3 * 16, 256), 256, 0, stream>>>(hb, selo3, vals, INb, N3);
        k_partial2<<<B * PSPLIT, 64, 0, stream>>>(INb, K3, part);
        k_sumreduce2<<<B, 256, 0, stream>>>(part, K3, summary, 1);
    }

    // ================= output =================
    k_out<<<B, OUTD, 0, stream>>>(summary, outW, outb, out);
}